// Round 1
// baseline (1198.869 us; speedup 1.0000x reference)
//
#include <hip/hip_runtime.h>
#include <cstdint>
#include <cstddef>

using short8   = __attribute__((ext_vector_type(8))) short;
using f32x4    = __attribute__((ext_vector_type(4))) float;
using ushort4v = __attribute__((ext_vector_type(4))) unsigned short;

#define DEV static __device__ __forceinline__

constexpr int NB  = 4;
constexpr int SEQ = 4096;
constexpr int DM  = 1024;
constexpr int BSR = NB * SEQ;   // 16384 flattened rows

DEV unsigned short f2bf(float f) {
  union { float f; unsigned u; } v; v.f = f;
  unsigned r = v.u + 0x7FFFu + ((v.u >> 16) & 1u);  // RNE
  return (unsigned short)(r >> 16);
}

DEV void gload_lds16(const void* g, void* l) {
  __builtin_amdgcn_global_load_lds(
      (__attribute__((address_space(1))) void*)(g),
      (__attribute__((address_space(3))) void*)(l), 16, 0, 0);
}

DEV f32x4 mfma16(short8 a, short8 b, f32x4 c) {
  return __builtin_amdgcn_mfma_f32_16x16x32_bf16(a, b, c, 0, 0, 0);
}

// RoPE-pair permutation: orig row index for permuted position p.
// p = (j>>4)*32 + (j&15) for j<512 ; p = (j>>4)*32 + 16 + (j&15) for j>=512.
DEV int orig_row(int p) {
  int gI = p >> 5, rr = p & 31;
  return (rr < 16) ? (gI * 16 + rr) : (512 + gI * 16 + (rr - 16));
}

// ---------------- conversion / permutation ----------------
__global__ __launch_bounds__(256) void convert_kernel(
    const float* __restrict__ x,
    const float* __restrict__ Wq, const float* __restrict__ Wk, const float* __restrict__ Wv,
    const float* __restrict__ bq, const float* __restrict__ bk, const float* __restrict__ bv,
    unsigned short* __restrict__ xbf,
    unsigned short* __restrict__ Wqp, unsigned short* __restrict__ Wkp, unsigned short* __restrict__ Wvp,
    float* __restrict__ bqp, float* __restrict__ bkp, float* __restrict__ bvp)
{
  const int U1 = BSR * DM / 8;        // x units (8 elems each)
  const int U2 = 2 * DM * DM / 8;     // Wq + Wk
  const int U3 = DM * DM / 8;         // Wv
  const int U4 = 3 * DM / 8;          // biases
  const int total = U1 + U2 + U3 + U4;
  for (int u = blockIdx.x * blockDim.x + threadIdx.x; u < total;
       u += gridDim.x * blockDim.x) {
    if (u < U1) {
      int e = u * 8;
      float4 f0 = ((const float4*)(x + e))[0];
      float4 f1 = ((const float4*)(x + e))[1];
      short8 o;
      o[0]=(short)f2bf(f0.x); o[1]=(short)f2bf(f0.y); o[2]=(short)f2bf(f0.z); o[3]=(short)f2bf(f0.w);
      o[4]=(short)f2bf(f1.x); o[5]=(short)f2bf(f1.y); o[6]=(short)f2bf(f1.z); o[7]=(short)f2bf(f1.w);
      *(short8*)(xbf + e) = o;
    } else if (u < U1 + U2) {
      int w = u - U1;
      int which = w >> 17;            // 0 = Wq, 1 = Wk
      int r = w & (131072 - 1);
      int p = r >> 7;
      int m8 = (r & 127) * 8;
      const float* src = (which ? Wk : Wq) + (size_t)orig_row(p) * DM + m8;
      unsigned short* dst = (which ? Wkp : Wqp) + (size_t)p * DM + m8;
      float4 f0 = ((const float4*)src)[0];
      float4 f1 = ((const float4*)src)[1];
      short8 o;
      o[0]=(short)f2bf(f0.x); o[1]=(short)f2bf(f0.y); o[2]=(short)f2bf(f0.z); o[3]=(short)f2bf(f0.w);
      o[4]=(short)f2bf(f1.x); o[5]=(short)f2bf(f1.y); o[6]=(short)f2bf(f1.z); o[7]=(short)f2bf(f1.w);
      *(short8*)dst = o;
    } else if (u < U1 + U2 + U3) {
      int r = u - (U1 + U2);
      int p = r >> 7;
      int m8 = (r & 127) * 8;
      const float* src = Wv + (size_t)p * DM + m8;
      float4 f0 = ((const float4*)src)[0];
      float4 f1 = ((const float4*)src)[1];
      short8 o;
      o[0]=(short)f2bf(f0.x); o[1]=(short)f2bf(f0.y); o[2]=(short)f2bf(f0.z); o[3]=(short)f2bf(f0.w);
      o[4]=(short)f2bf(f1.x); o[5]=(short)f2bf(f1.y); o[6]=(short)f2bf(f1.z); o[7]=(short)f2bf(f1.w);
      *(short8*)(Wvp + (size_t)p * DM + m8) = o;
    } else {
      int t = u - (U1 + U2 + U3);
      int which = t >> 7;
      int i0 = (t & 127) * 8;
      for (int e = 0; e < 8; ++e) {
        int p = i0 + e;
        if (which == 0)      bqp[p] = bq[orig_row(p)];
        else if (which == 1) bkp[p] = bk[orig_row(p)];
        else                 bvp[p] = bv[p];
      }
    }
  }
}

// ---------------- projection GEMM: C = X * W^T (+bias, +rope / +transpose) ----------------
// MODE 0: rope epilogue, out row-major [BSR][DM] bf16 (permuted cols)
// MODE 1: bias epilogue, out transposed [NB][DM][SEQ] bf16
template <int MODE>
__global__ __launch_bounds__(256, 3) void gemm_kernel(
    const unsigned short* __restrict__ X,   // [BSR][DM] bf16
    const unsigned short* __restrict__ W,   // [DM][DM] bf16 (rows = out cols)
    const float* __restrict__ bias,
    const float* __restrict__ cosT, const float* __restrict__ sinT, // [SEQ][DM/2]
    unsigned short* __restrict__ out)
{
  __shared__ unsigned short As[128 * 32];
  __shared__ unsigned short Bs[128 * 32];
  const int tid = threadIdx.x, wid = tid >> 6, lane = tid & 63;
  const int c = lane & 15, g = lane >> 4;
  const int wm = wid >> 1, wn = wid & 1;
  const int bm = blockIdx.y * 128, bn = blockIdx.x * 128;

  f32x4 zero4 = {0.f, 0.f, 0.f, 0.f};
  f32x4 acc[4][4];
  for (int m = 0; m < 4; ++m) for (int n = 0; n < 4; ++n) acc[m][n] = zero4;

  for (int kt = 0; kt < 32; ++kt) {
    const int k0 = kt * 32;
    for (int i = 0; i < 2; ++i) {
      int ch = wid * 2 + i;                 // 1KB chunk, wave-uniform dest
      int row = ch * 16 + (lane >> 2);
      int kk = (lane & 3) * 8;
      gload_lds16(X + (size_t)(bm + row) * DM + k0 + kk, (void*)(As + ch * 512));
      gload_lds16(W + (size_t)(bn + row) * DM + k0 + kk, (void*)(Bs + ch * 512));
    }
    __syncthreads();
    short8 a[4], b[4];
    for (int m = 0; m < 4; ++m)
      a[m] = *(const short8*)(As + (wm * 64 + m * 16 + c) * 32 + g * 8);
    for (int n = 0; n < 4; ++n)
      b[n] = *(const short8*)(Bs + (wn * 64 + n * 16 + c) * 32 + g * 8);
    for (int m = 0; m < 4; ++m)
      for (int n = 0; n < 4; ++n)
        acc[m][n] = mfma16(a[m], b[n], acc[m][n]);
    __syncthreads();
  }

  if (MODE == 0) {
    for (int m = 0; m < 4; ++m) {
      int row0 = bm + wm * 64 + m * 16 + g * 4;
      for (int fp = 0; fp < 4; fp += 2) {
        int f_g = (bn >> 4) + wn * 4 + fp;        // global 16-col fragment index
        float b0 = bias[f_g * 16 + c];
        float b1 = bias[(f_g + 1) * 16 + c];
        int j = (f_g >> 1) * 16 + c;              // rope pair index < 512
        for (int r = 0; r < 4; ++r) {
          int rowg = row0 + r;
          int s = rowg & (SEQ - 1);
          float x0 = acc[m][fp][r] + b0;
          float x1 = acc[m][fp + 1][r] + b1;
          float cv = cosT[(size_t)s * (DM / 2) + j];
          float sv = sinT[(size_t)s * (DM / 2) + j];
          out[(size_t)rowg * DM + f_g * 16 + c]       = f2bf(x0 * cv - x1 * sv);
          out[(size_t)rowg * DM + (f_g + 1) * 16 + c] = f2bf(x0 * sv + x1 * cv);
        }
      }
    }
  } else {
    for (int m = 0; m < 4; ++m) {
      int s0 = bm + wm * 64 + m * 16 + g * 4;
      int bb = s0 >> 12;
      int sl = s0 & (SEQ - 1);
      for (int f = 0; f < 4; ++f) {
        int v = bn + wn * 64 + f * 16 + c;
        float bv_ = bias[v];
        ushort4v pk;
        for (int r = 0; r < 4; ++r) pk[r] = f2bf(acc[m][f][r] + bv_);
        *(ushort4v*)(out + ((size_t)(bb * DM + v)) * SEQ + sl) = pk;
      }
    }
  }
}

// ---------------- flash attention ----------------
// QBLK=32, KVBLK=128, 8 waves (512 thr). QK^T: waves 2q x 4kv (16x32 each).
// PV: each wave owns a 128-wide V column slice. V is pre-transposed [NB][DM][SEQ].
__global__ __launch_bounds__(512, 4) void attn_kernel(
    const unsigned short* __restrict__ Qbf,
    const unsigned short* __restrict__ Kbf,
    const unsigned short* __restrict__ Vt,
    float* __restrict__ z)
{
  __shared__ unsigned short Qs[32 * 1032];  // padded rows: 2-way-free LDS banks
  __shared__ unsigned short Ps[32 * 136];
  __shared__ float m_run[32], l_run[32], osc[32];
  __shared__ float wmax[4][32], wsum[4][32];

  const int tid = threadIdx.x, wid = tid >> 6, lane = tid & 63;
  const int c = lane & 15, g = lane >> 4;
  const int batch = blockIdx.x & 3;
  const int qt = 127 - (blockIdx.x >> 2);   // descending work (causal balance)
  const int q0 = qt * 32;
  const int wq = wid >> 2, wk = wid & 3;

  for (int i = 0; i < 8; ++i) {             // stage Q tile 32x1024
    int ch = wid * 8 + i;
    int r = ch >> 1, h = ch & 1;
    gload_lds16(Qbf + ((size_t)(batch * SEQ + q0 + r)) * DM + h * 512 + lane * 8,
                (void*)(Qs + r * 1032 + h * 512));
  }
  if (tid < 32) { m_run[tid] = -1e30f; l_run[tid] = 0.f; }
  __syncthreads();

  f32x4 zero4 = {0.f, 0.f, 0.f, 0.f};
  f32x4 acc[2][8];
  for (int m = 0; m < 2; ++m) for (int v = 0; v < 8; ++v) acc[m][v] = zero4;

  const int ntiles = ((q0 + 31) >> 7) + 1;
  const unsigned short* Kbase = Kbf + (size_t)(batch * SEQ) * DM;
  const unsigned short* Vbase = Vt + (size_t)batch * DM * SEQ + (size_t)(wid * 128) * SEQ;
  const unsigned short* Qrow = Qs + (wq * 16 + c) * 1032 + g * 8;
  const int qrow_base = q0 + wq * 16 + g * 4;

  for (int tt = 0; tt < ntiles; ++tt) {
    const int kv0 = tt * 128;
    // ---- QK^T ----
    f32x4 sa0 = zero4, sa1 = zero4;
    const unsigned short* kp0 = Kbase + (size_t)(kv0 + wk * 32 + c) * DM + g * 8;
    const unsigned short* kp1 = kp0 + (size_t)16 * DM;
    #pragma unroll 4
    for (int ks = 0; ks < 32; ++ks) {
      short8 qa = *(const short8*)(Qrow + ks * 32);
      short8 k0 = *(const short8*)(kp0 + ks * 32);
      short8 k1 = *(const short8*)(kp1 + ks * 32);
      sa0 = mfma16(qa, k0, sa0);
      sa1 = mfma16(qa, k1, sa1);
    }
    // scale + causal mask + per-row tile max
    const float scale = 0.03125f;  // 1/sqrt(1024)
    const int t0c = kv0 + wk * 32 + c;
    float tm[4];
    #pragma unroll
    for (int r = 0; r < 4; ++r) {
      float v0 = sa0[r] * scale;
      float v1 = sa1[r] * scale;
      int qr = qrow_base + r;
      if (t0c > qr)      v0 = -1e30f;
      if (t0c + 16 > qr) v1 = -1e30f;
      sa0[r] = v0; sa1[r] = v1;
      tm[r] = fmaxf(v0, v1);
    }
    #pragma unroll
    for (int mm = 1; mm < 16; mm <<= 1)
      for (int r = 0; r < 4; ++r) tm[r] = fmaxf(tm[r], __shfl_xor(tm[r], mm, 64));
    if (c == 0)
      for (int r = 0; r < 4; ++r) wmax[wk][wq * 16 + g * 4 + r] = tm[r];
    __syncthreads();                         // b1
    if (wid == 0 && lane < 32) {
      int row = lane;
      float t = fmaxf(fmaxf(wmax[0][row], wmax[1][row]), fmaxf(wmax[2][row], wmax[3][row]));
      float mo = m_run[row];
      float mn = fmaxf(mo, t);
      m_run[row] = mn;
      osc[row] = __expf(mo - mn);
    }
    __syncthreads();                         // b2
    float rs[4];
    #pragma unroll
    for (int r = 0; r < 4; ++r) {
      int lrow = wq * 16 + g * 4 + r;
      float mn = m_run[lrow];
      float p0 = __expf(sa0[r] - mn);
      float p1 = __expf(sa1[r] - mn);
      Ps[lrow * 136 + wk * 32 + c]      = f2bf(p0);
      Ps[lrow * 136 + wk * 32 + 16 + c] = f2bf(p1);
      rs[r] = p0 + p1;
    }
    #pragma unroll
    for (int mm = 1; mm < 16; mm <<= 1)
      for (int r = 0; r < 4; ++r) rs[r] += __shfl_xor(rs[r], mm, 64);
    if (c == 0)
      for (int r = 0; r < 4; ++r) wsum[wk][wq * 16 + g * 4 + r] = rs[r];
    __syncthreads();                         // b3
    if (wid == 0 && lane < 32) {
      int row = lane;
      l_run[row] = l_run[row] * osc[row] +
                   wsum[0][row] + wsum[1][row] + wsum[2][row] + wsum[3][row];
    }
    // ---- PV ----
    float os[2][4];
    #pragma unroll
    for (int m = 0; m < 2; ++m)
      for (int r = 0; r < 4; ++r) os[m][r] = osc[m * 16 + g * 4 + r];
    #pragma unroll
    for (int m = 0; m < 2; ++m)
      for (int v = 0; v < 8; ++v)
        for (int r = 0; r < 4; ++r) acc[m][v][r] *= os[m][r];
    #pragma unroll 1
    for (int ks = 0; ks < 4; ++ks) {
      short8 pa0 = *(const short8*)(Ps + c * 136 + ks * 32 + g * 8);
      short8 pa1 = *(const short8*)(Ps + (16 + c) * 136 + ks * 32 + g * 8);
      #pragma unroll
      for (int vf = 0; vf < 8; ++vf) {
        short8 vb = *(const short8*)(Vbase + (size_t)(vf * 16 + c) * SEQ + kv0 + ks * 32 + g * 8);
        acc[0][vf] = mfma16(pa0, vb, acc[0][vf]);
        acc[1][vf] = mfma16(pa1, vb, acc[1][vf]);
      }
    }
  }
  __syncthreads();
  // epilogue: divide by softmax denom, write fp32
  for (int m = 0; m < 2; ++m) {
    for (int r = 0; r < 4; ++r) {
      int lrow = m * 16 + g * 4 + r;
      float inv = 1.0f / l_run[lrow];
      int qg = q0 + lrow;
      float* zp = z + ((size_t)(batch * SEQ + qg)) * DM + wid * 128;
      #pragma unroll
      for (int v = 0; v < 8; ++v) zp[v * 16 + c] = acc[m][v][r] * inv;
    }
  }
}

extern "C" void kernel_launch(void* const* d_in, const int* in_sizes, int n_in,
                              void* d_out, int out_size, void* d_ws, size_t ws_size,
                              hipStream_t stream) {
  const float* x    = (const float*)d_in[0];
  const float* cosT = (const float*)d_in[1];
  const float* sinT = (const float*)d_in[2];
  const float* Wq   = (const float*)d_in[3];
  const float* bq   = (const float*)d_in[4];
  const float* Wk   = (const float*)d_in[5];
  const float* bk   = (const float*)d_in[6];
  const float* Wv   = (const float*)d_in[7];
  const float* bv   = (const float*)d_in[8];
  float* z = (float*)d_out;

  char* ws = (char*)d_ws;
  unsigned short* xbf = (unsigned short*)(ws);
  unsigned short* Wqp = (unsigned short*)(ws + 33554432);
  unsigned short* Wkp = (unsigned short*)(ws + 35651584);
  unsigned short* Wvp = (unsigned short*)(ws + 37748736);
  float* bqp = (float*)(ws + 39845888);
  float* bkp = (float*)(ws + 39849984);
  float* bvp = (float*)(ws + 39854080);
  unsigned short* Qbf = (unsigned short*)(ws + 39858176);
  unsigned short* Kbf = (unsigned short*)(ws + 73412608);
  unsigned short* Vtb = (unsigned short*)(ws + 106967040);
  // total workspace use: 140,521,472 bytes

  convert_kernel<<<dim3(2048), dim3(256), 0, stream>>>(
      x, Wq, Wk, Wv, bq, bk, bv, xbf, Wqp, Wkp, Wvp, bqp, bkp, bvp);

  dim3 gg(8, 128);
  gemm_kernel<0><<<gg, dim3(256), 0, stream>>>(xbf, Wqp, bqp, cosT, sinT, Qbf);
  gemm_kernel<0><<<gg, dim3(256), 0, stream>>>(xbf, Wkp, bkp, cosT, sinT, Kbf);
  gemm_kernel<1><<<gg, dim3(256), 0, stream>>>(xbf, Wvp, bvp, cosT, sinT, Vtb);

  attn_kernel<<<dim3(512), dim3(512), 0, stream>>>(Qbf, Kbf, Vtb, z);
}

// Round 2
// 459.760 us; speedup vs baseline: 2.6076x; 2.6076x over previous
//
#include <hip/hip_runtime.h>
#include <cstdint>
#include <cstddef>

using short8   = __attribute__((ext_vector_type(8))) short;
using f32x4    = __attribute__((ext_vector_type(4))) float;
using ushort4v = __attribute__((ext_vector_type(4))) unsigned short;

#define DEV static __device__ __forceinline__

constexpr int NB  = 4;
constexpr int SEQ = 4096;
constexpr int DM  = 1024;
constexpr int BSR = NB * SEQ;   // 16384 flattened rows
constexpr int TRI = 528;        // causal 128x128 tiles per batch (32*33/2)

DEV unsigned short f2bf(float f) {
  union { float f; unsigned u; } v; v.f = f;
  unsigned r = v.u + 0x7FFFu + ((v.u >> 16) & 1u);  // RNE
  return (unsigned short)(r >> 16);
}

DEV int tri(int t) { return t * (t + 1) / 2; }

DEV void gload_lds16(const void* g, void* l) {
  __builtin_amdgcn_global_load_lds(
      (__attribute__((address_space(1))) void*)(g),
      (__attribute__((address_space(3))) void*)(l), 16, 0, 0);
}

DEV f32x4 mfma16(short8 a, short8 b, f32x4 c) {
  return __builtin_amdgcn_mfma_f32_16x16x32_bf16(a, b, c, 0, 0, 0);
}

// RoPE-pair permutation: orig row index for permuted position p.
DEV int orig_row(int p) {
  int gI = p >> 5, rr = p & 31;
  return (rr < 16) ? (gI * 16 + rr) : (512 + gI * 16 + (rr - 16));
}

// ---------------- conversion / permutation ----------------
__global__ __launch_bounds__(256) void convert_kernel(
    const float* __restrict__ x,
    const float* __restrict__ Wq, const float* __restrict__ Wk, const float* __restrict__ Wv,
    const float* __restrict__ bq, const float* __restrict__ bk, const float* __restrict__ bv,
    unsigned short* __restrict__ xbf,
    unsigned short* __restrict__ Wqp, unsigned short* __restrict__ Wkp, unsigned short* __restrict__ Wvp,
    float* __restrict__ bqp, float* __restrict__ bkp, float* __restrict__ bvp)
{
  const int U1 = BSR * DM / 8;
  const int U2 = 2 * DM * DM / 8;
  const int U3 = DM * DM / 8;
  const int U4 = 3 * DM / 8;
  const int total = U1 + U2 + U3 + U4;
  for (int u = blockIdx.x * blockDim.x + threadIdx.x; u < total;
       u += gridDim.x * blockDim.x) {
    if (u < U1) {
      int e = u * 8;
      float4 f0 = ((const float4*)(x + e))[0];
      float4 f1 = ((const float4*)(x + e))[1];
      short8 o;
      o[0]=(short)f2bf(f0.x); o[1]=(short)f2bf(f0.y); o[2]=(short)f2bf(f0.z); o[3]=(short)f2bf(f0.w);
      o[4]=(short)f2bf(f1.x); o[5]=(short)f2bf(f1.y); o[6]=(short)f2bf(f1.z); o[7]=(short)f2bf(f1.w);
      *(short8*)(xbf + e) = o;
    } else if (u < U1 + U2) {
      int w = u - U1;
      int which = w >> 17;
      int r = w & (131072 - 1);
      int p = r >> 7;
      int m8 = (r & 127) * 8;
      const float* src = (which ? Wk : Wq) + (size_t)orig_row(p) * DM + m8;
      unsigned short* dst = (which ? Wkp : Wqp) + (size_t)p * DM + m8;
      float4 f0 = ((const float4*)src)[0];
      float4 f1 = ((const float4*)src)[1];
      short8 o;
      o[0]=(short)f2bf(f0.x); o[1]=(short)f2bf(f0.y); o[2]=(short)f2bf(f0.z); o[3]=(short)f2bf(f0.w);
      o[4]=(short)f2bf(f1.x); o[5]=(short)f2bf(f1.y); o[6]=(short)f2bf(f1.z); o[7]=(short)f2bf(f1.w);
      *(short8*)dst = o;
    } else if (u < U1 + U2 + U3) {
      int r = u - (U1 + U2);
      int p = r >> 7;
      int m8 = (r & 127) * 8;
      const float* src = Wv + (size_t)p * DM + m8;
      float4 f0 = ((const float4*)src)[0];
      float4 f1 = ((const float4*)src)[1];
      short8 o;
      o[0]=(short)f2bf(f0.x); o[1]=(short)f2bf(f0.y); o[2]=(short)f2bf(f0.z); o[3]=(short)f2bf(f0.w);
      o[4]=(short)f2bf(f1.x); o[5]=(short)f2bf(f1.y); o[6]=(short)f2bf(f1.z); o[7]=(short)f2bf(f1.w);
      *(short8*)(Wvp + (size_t)p * DM + m8) = o;
    } else {
      int t = u - (U1 + U2 + U3);
      int which = t >> 7;
      int i0 = (t & 127) * 8;
      for (int e = 0; e < 8; ++e) {
        int p = i0 + e;
        if (which == 0)      bqp[p] = bq[orig_row(p)];
        else if (which == 1) bkp[p] = bk[orig_row(p)];
        else                 bvp[p] = bv[p];
      }
    }
  }
}

// ---------------- GEMM: C = X * W^T ----------------
// MODE 0: rope epilogue, out row-major [BSR][DM] bf16 (permuted cols)
// MODE 1: bias epilogue, out transposed [NB][DM][SEQ] bf16
// MODE 2: scores: X=Q, W=K (per batch), out = packed causal tiles fp16 raw
template <int MODE>
__global__ __launch_bounds__(256, 3) void gemm_proj(
    const unsigned short* __restrict__ Xin,
    const unsigned short* __restrict__ Win,
    const float* __restrict__ bias,
    const float* __restrict__ cosT, const float* __restrict__ sinT,
    unsigned short* __restrict__ out, int b0)
{
  __shared__ unsigned short As[128 * 32];
  __shared__ unsigned short Bs[128 * 32];
  const int tid = threadIdx.x, wid = tid >> 6, lane = tid & 63;
  const int c = lane & 15, g = lane >> 4;
  const int wm = wid >> 1, wn = wid & 1;

  const unsigned short* X;
  const unsigned short* W;
  int bm, bn;
  size_t tile_off = 0;
  if (MODE == 2) {
    int idx = blockIdx.x;
    int tm = (int)((sqrtf(8.0f * (float)idx + 1.0f) - 1.0f) * 0.5f);
    while (tri(tm + 1) <= idx) ++tm;
    while (tri(tm) > idx) --tm;
    int tn = idx - tri(tm);
    int b = b0 + blockIdx.y;
    bm = tm * 128; bn = tn * 128;
    X = Xin + (size_t)b * SEQ * DM;
    W = Win + (size_t)b * SEQ * DM;
    tile_off = ((size_t)blockIdx.y * TRI + idx) * 16384;
  } else {
    bm = blockIdx.y * 128; bn = blockIdx.x * 128;
    X = Xin; W = Win;
  }

  f32x4 zero4 = {0.f, 0.f, 0.f, 0.f};
  f32x4 acc[4][4];
  for (int m = 0; m < 4; ++m) for (int n = 0; n < 4; ++n) acc[m][n] = zero4;

  for (int kt = 0; kt < 32; ++kt) {
    const int k0 = kt * 32;
    for (int i = 0; i < 2; ++i) {
      int ch = wid * 2 + i;
      int row = ch * 16 + (lane >> 2);
      int kk = (lane & 3) * 8;
      gload_lds16(X + (size_t)(bm + row) * DM + k0 + kk, (void*)(As + ch * 512));
      gload_lds16(W + (size_t)(bn + row) * DM + k0 + kk, (void*)(Bs + ch * 512));
    }
    __syncthreads();
    short8 a[4], b[4];
    for (int m = 0; m < 4; ++m)
      a[m] = *(const short8*)(As + (wm * 64 + m * 16 + c) * 32 + g * 8);
    for (int n = 0; n < 4; ++n)
      b[n] = *(const short8*)(Bs + (wn * 64 + n * 16 + c) * 32 + g * 8);
    for (int m = 0; m < 4; ++m)
      for (int n = 0; n < 4; ++n)
        acc[m][n] = mfma16(a[m], b[n], acc[m][n]);
    __syncthreads();
  }

  if (MODE == 0) {
    for (int m = 0; m < 4; ++m) {
      int row0 = bm + wm * 64 + m * 16 + g * 4;
      for (int fp = 0; fp < 4; fp += 2) {
        int f_g = (bn >> 4) + wn * 4 + fp;
        float b0f = bias[f_g * 16 + c];
        float b1f = bias[(f_g + 1) * 16 + c];
        int j = (f_g >> 1) * 16 + c;
        for (int r = 0; r < 4; ++r) {
          int rowg = row0 + r;
          int s = rowg & (SEQ - 1);
          float x0 = acc[m][fp][r] + b0f;
          float x1 = acc[m][fp + 1][r] + b1f;
          float cv = cosT[(size_t)s * (DM / 2) + j];
          float sv = sinT[(size_t)s * (DM / 2) + j];
          out[(size_t)rowg * DM + f_g * 16 + c]       = f2bf(x0 * cv - x1 * sv);
          out[(size_t)rowg * DM + (f_g + 1) * 16 + c] = f2bf(x0 * sv + x1 * cv);
        }
      }
    }
  } else if (MODE == 1) {
    for (int m = 0; m < 4; ++m) {
      int s0 = bm + wm * 64 + m * 16 + g * 4;
      int bb = s0 >> 12;
      int sl = s0 & (SEQ - 1);
      for (int f = 0; f < 4; ++f) {
        int v = bn + wn * 64 + f * 16 + c;
        float bv_ = bias[v];
        ushort4v pk;
        for (int r = 0; r < 4; ++r) pk[r] = f2bf(acc[m][f][r] + bv_);
        *(ushort4v*)(out + ((size_t)(bb * DM + v)) * SEQ + sl) = pk;
      }
    }
  } else {
    unsigned short* tb = out + tile_off;
    for (int m = 0; m < 4; ++m) {
      int row0 = wm * 64 + m * 16 + g * 4;
      for (int n = 0; n < 4; ++n) {
        int col = wn * 64 + n * 16 + c;
        for (int r = 0; r < 4; ++r) {
          union { _Float16 h; unsigned short u; } cv;
          cv.h = (_Float16)acc[m][n][r];
          tb[(size_t)(row0 + r) * 128 + col] = cv.u;
        }
      }
    }
  }
}

// ---------------- row softmax over packed causal tiles (in place) ----------------
// Reads fp16 raw scores, writes normalized bf16 P. One wave per q-row.
__global__ __launch_bounds__(256) void softmax_kernel(unsigned short* __restrict__ S_)
{
  const int tid = threadIdx.x, wid = tid >> 6, lane = tid & 63;
  const int widx = blockIdx.x * 4 + wid;
  const int li = widx >> 12;           // group-local batch
  const int r = widx & (SEQ - 1);
  unsigned short* Pb = S_ + (size_t)li * TRI * 16384;
  const int tmr = r >> 7, rr = r & 127;
  const float K2 = 0.04508422002778011f;  // (1/32) * log2(e)

  float v0[32], v1[32];
  float mx = -3.0e38f;
  #pragma unroll
  for (int tn = 0; tn < 32; ++tn) {
    if (tn <= tmr) {
      unsigned u = *(const unsigned*)(Pb + ((size_t)(tri(tmr) + tn)) * 16384 + rr * 128 + lane * 2);
      union { unsigned u; _Float16 h[2]; } cv; cv.u = u;
      int col = tn * 128 + lane * 2;
      float a0 = (col     <= r) ? (float)cv.h[0] : -3.0e38f;
      float a1 = (col + 1 <= r) ? (float)cv.h[1] : -3.0e38f;
      v0[tn] = a0; v1[tn] = a1;
      mx = fmaxf(mx, fmaxf(a0, a1));
    }
  }
  #pragma unroll
  for (int d = 1; d < 64; d <<= 1) mx = fmaxf(mx, __shfl_xor(mx, d, 64));
  float sum = 0.f;
  #pragma unroll
  for (int tn = 0; tn < 32; ++tn) {
    if (tn <= tmr) {
      float p0 = (v0[tn] < -1.0e37f) ? 0.f : exp2f((v0[tn] - mx) * K2);
      float p1 = (v1[tn] < -1.0e37f) ? 0.f : exp2f((v1[tn] - mx) * K2);
      v0[tn] = p0; v1[tn] = p1;
      sum += p0 + p1;
    }
  }
  #pragma unroll
  for (int d = 1; d < 64; d <<= 1) sum += __shfl_xor(sum, d, 64);
  float inv = 1.0f / sum;
  #pragma unroll
  for (int tn = 0; tn < 32; ++tn) {
    if (tn <= tmr) {
      unsigned o = (unsigned)f2bf(v0[tn] * inv) | ((unsigned)f2bf(v1[tn] * inv) << 16);
      *(unsigned*)(Pb + ((size_t)(tri(tmr) + tn)) * 16384 + rr * 128 + lane * 2) = o;
    }
  }
}

// ---------------- PV GEMM: z = P * V (V^T stored) ----------------
// P packed causal bf16 tiles; W = Vt [NB][DM][SEQ]; out z fp32 [BSR][DM].
// Each block does paired q-tiles (pr, 31-pr) -> uniform 132 K-steps.
__global__ __launch_bounds__(256, 3) void gemm_pv(
    const unsigned short* __restrict__ P,
    const unsigned short* __restrict__ Vt,
    float* __restrict__ z, int b0)
{
  __shared__ unsigned short As[128 * 32];
  __shared__ unsigned short Bs[128 * 32];
  const int tid = threadIdx.x, wid = tid >> 6, lane = tid & 63;
  const int c = lane & 15, g = lane >> 4;
  const int wm = wid >> 1, wn = wid & 1;
  const int li = blockIdx.y, b = b0 + li;
  const int n_ = blockIdx.x & 7, pr = blockIdx.x >> 3;
  const unsigned short* Pb = P + (size_t)li * TRI * 16384;
  const int bn = n_ * 128;

  f32x4 zero4 = {0.f, 0.f, 0.f, 0.f};
  for (int half = 0; half < 2; ++half) {
    const int tm = half ? (31 - pr) : pr;
    const int bm = tm * 128;
    f32x4 acc[4][4];
    for (int m = 0; m < 4; ++m) for (int n = 0; n < 4; ++n) acc[m][n] = zero4;

    const int nkt = (tm + 1) * 4;
    const size_t tribase = (size_t)tri(tm) * 16384;
    for (int kt = 0; kt < nkt; ++kt) {
      const int k0 = kt * 32;
      const int tk = k0 >> 7, off = k0 & 127;
      const unsigned short* Abase = Pb + tribase + (size_t)tk * 16384 + off;
      for (int i = 0; i < 2; ++i) {
        int ch = wid * 2 + i;
        int row = ch * 16 + (lane >> 2);
        int kk = (lane & 3) * 8;
        gload_lds16(Abase + row * 128 + kk, (void*)(As + ch * 512));
        gload_lds16(Vt + ((size_t)(b * DM + bn + row)) * SEQ + k0 + kk, (void*)(Bs + ch * 512));
      }
      __syncthreads();
      short8 a[4], bb[4];
      for (int m = 0; m < 4; ++m)
        a[m] = *(const short8*)(As + (wm * 64 + m * 16 + c) * 32 + g * 8);
      for (int n = 0; n < 4; ++n)
        bb[n] = *(const short8*)(Bs + (wn * 64 + n * 16 + c) * 32 + g * 8);
      for (int m = 0; m < 4; ++m)
        for (int n = 0; n < 4; ++n)
          acc[m][n] = mfma16(a[m], bb[n], acc[m][n]);
      __syncthreads();
    }

    for (int m = 0; m < 4; ++m) {
      int row0 = bm + wm * 64 + m * 16 + g * 4;
      for (int n = 0; n < 4; ++n) {
        int col = bn + wn * 64 + n * 16 + c;
        for (int r = 0; r < 4; ++r)
          z[((size_t)(b * SEQ + row0 + r)) * DM + col] = acc[m][n][r];
      }
    }
  }
}

extern "C" void kernel_launch(void* const* d_in, const int* in_sizes, int n_in,
                              void* d_out, int out_size, void* d_ws, size_t ws_size,
                              hipStream_t stream) {
  const float* x    = (const float*)d_in[0];
  const float* cosT = (const float*)d_in[1];
  const float* sinT = (const float*)d_in[2];
  const float* Wq   = (const float*)d_in[3];
  const float* bq   = (const float*)d_in[4];
  const float* Wk   = (const float*)d_in[5];
  const float* bk   = (const float*)d_in[6];
  const float* Wv   = (const float*)d_in[7];
  const float* bv   = (const float*)d_in[8];
  float* z = (float*)d_out;

  char* ws = (char*)d_ws;
  unsigned short* xbf = (unsigned short*)(ws);
  unsigned short* Wqp = (unsigned short*)(ws + 33554432);
  unsigned short* Wkp = (unsigned short*)(ws + 35651584);
  unsigned short* Wvp = (unsigned short*)(ws + 37748736);
  float* bqp = (float*)(ws + 39845888);
  float* bkp = (float*)(ws + 39849984);
  float* bvp = (float*)(ws + 39854080);
  unsigned short* Qbf = (unsigned short*)(ws + 39858176);
  unsigned short* Kbf = (unsigned short*)(ws + 73412608);
  unsigned short* Vtb = (unsigned short*)(ws + 106967040);
  const size_t BASE = 140521472ULL;
  const size_t PER  = 17301504ULL;   // one batch of packed causal tiles (fp16/bf16)
  unsigned short* Sc = (unsigned short*)(ws + BASE);

  int G = 1;
  if (ws_size >= BASE + 4 * PER)      G = 4;
  else if (ws_size >= BASE + 2 * PER) G = 2;

  convert_kernel<<<dim3(2048), dim3(256), 0, stream>>>(
      x, Wq, Wk, Wv, bq, bk, bv, xbf, Wqp, Wkp, Wvp, bqp, bkp, bvp);

  dim3 gg(8, 128);
  gemm_proj<0><<<gg, dim3(256), 0, stream>>>(xbf, Wqp, bqp, cosT, sinT, Qbf, 0);
  gemm_proj<0><<<gg, dim3(256), 0, stream>>>(xbf, Wkp, bkp, cosT, sinT, Kbf, 0);
  gemm_proj<1><<<gg, dim3(256), 0, stream>>>(xbf, Wvp, bvp, cosT, sinT, Vtb, 0);

  for (int b0 = 0; b0 < NB; b0 += G) {
    gemm_proj<2><<<dim3(TRI, G), dim3(256), 0, stream>>>(Qbf, Kbf, nullptr, nullptr, nullptr, Sc, b0);
    softmax_kernel<<<dim3(1024 * G), dim3(256), 0, stream>>>(Sc);
    gemm_pv<<<dim3(128, G), dim3(256), 0, stream>>>(Sc, Vtb, z, b0);
  }
}

// Round 3
// 423.781 us; speedup vs baseline: 2.8290x; 1.0849x over previous
//
#include <hip/hip_runtime.h>
#include <cstdint>
#include <cstddef>

using short8   = __attribute__((ext_vector_type(8))) short;
using f32x4    = __attribute__((ext_vector_type(4))) float;
using ushort4v = __attribute__((ext_vector_type(4))) unsigned short;

#define DEV static __device__ __forceinline__

constexpr int NB  = 4;
constexpr int SEQ = 4096;
constexpr int DM  = 1024;
constexpr int BSR = NB * SEQ;   // 16384 flattened rows
constexpr int TRI = 528;        // causal 128x128 tiles per batch (32*33/2)

DEV unsigned short f2bf(float f) {
  union { float f; unsigned u; } v; v.f = f;
  unsigned r = v.u + 0x7FFFu + ((v.u >> 16) & 1u);  // RNE
  return (unsigned short)(r >> 16);
}

DEV int tri(int t) { return t * (t + 1) / 2; }

DEV void gload_lds16(const void* g, void* l) {
  __builtin_amdgcn_global_load_lds(
      (__attribute__((address_space(1))) void*)(g),
      (__attribute__((address_space(3))) void*)(l), 16, 0, 0);
}

DEV f32x4 mfma16(short8 a, short8 b, f32x4 c) {
  return __builtin_amdgcn_mfma_f32_16x16x32_bf16(a, b, c, 0, 0, 0);
}

// RoPE-pair permutation: orig row index for permuted position p.
DEV int orig_row(int p) {
  int gI = p >> 5, rr = p & 31;
  return (rr < 16) ? (gI * 16 + rr) : (512 + gI * 16 + (rr - 16));
}

// ---------------- conversion / permutation ----------------
__global__ __launch_bounds__(256) void convert_kernel(
    const float* __restrict__ x,
    const float* __restrict__ Wq, const float* __restrict__ Wk, const float* __restrict__ Wv,
    const float* __restrict__ bq, const float* __restrict__ bk, const float* __restrict__ bv,
    unsigned short* __restrict__ xbf,
    unsigned short* __restrict__ Wqp, unsigned short* __restrict__ Wkp, unsigned short* __restrict__ Wvp,
    float* __restrict__ bqp, float* __restrict__ bkp, float* __restrict__ bvp)
{
  const int U1 = BSR * DM / 8;
  const int U2 = 2 * DM * DM / 8;
  const int U3 = DM * DM / 8;
  const int U4 = 3 * DM / 8;
  const int total = U1 + U2 + U3 + U4;
  for (int u = blockIdx.x * blockDim.x + threadIdx.x; u < total;
       u += gridDim.x * blockDim.x) {
    if (u < U1) {
      int e = u * 8;
      float4 f0 = ((const float4*)(x + e))[0];
      float4 f1 = ((const float4*)(x + e))[1];
      short8 o;
      o[0]=(short)f2bf(f0.x); o[1]=(short)f2bf(f0.y); o[2]=(short)f2bf(f0.z); o[3]=(short)f2bf(f0.w);
      o[4]=(short)f2bf(f1.x); o[5]=(short)f2bf(f1.y); o[6]=(short)f2bf(f1.z); o[7]=(short)f2bf(f1.w);
      *(short8*)(xbf + e) = o;
    } else if (u < U1 + U2) {
      int w = u - U1;
      int which = w >> 17;
      int r = w & (131072 - 1);
      int p = r >> 7;
      int m8 = (r & 127) * 8;
      const float* src = (which ? Wk : Wq) + (size_t)orig_row(p) * DM + m8;
      unsigned short* dst = (which ? Wkp : Wqp) + (size_t)p * DM + m8;
      float4 f0 = ((const float4*)src)[0];
      float4 f1 = ((const float4*)src)[1];
      short8 o;
      o[0]=(short)f2bf(f0.x); o[1]=(short)f2bf(f0.y); o[2]=(short)f2bf(f0.z); o[3]=(short)f2bf(f0.w);
      o[4]=(short)f2bf(f1.x); o[5]=(short)f2bf(f1.y); o[6]=(short)f2bf(f1.z); o[7]=(short)f2bf(f1.w);
      *(short8*)dst = o;
    } else if (u < U1 + U2 + U3) {
      int r = u - (U1 + U2);
      int p = r >> 7;
      int m8 = (r & 127) * 8;
      const float* src = Wv + (size_t)p * DM + m8;
      float4 f0 = ((const float4*)src)[0];
      float4 f1 = ((const float4*)src)[1];
      short8 o;
      o[0]=(short)f2bf(f0.x); o[1]=(short)f2bf(f0.y); o[2]=(short)f2bf(f0.z); o[3]=(short)f2bf(f0.w);
      o[4]=(short)f2bf(f1.x); o[5]=(short)f2bf(f1.y); o[6]=(short)f2bf(f1.z); o[7]=(short)f2bf(f1.w);
      *(short8*)(Wvp + (size_t)p * DM + m8) = o;
    } else {
      int t = u - (U1 + U2 + U3);
      int which = t >> 7;
      int i0 = (t & 127) * 8;
      for (int e = 0; e < 8; ++e) {
        int p = i0 + e;
        if (which == 0)      bqp[p] = bq[orig_row(p)];
        else if (which == 1) bkp[p] = bk[orig_row(p)];
        else                 bvp[p] = bv[p];
      }
    }
  }
}

// ---------------- GEMM: C = X * W^T ----------------
// MODE 0: rope epilogue, out row-major [BSR][DM] bf16 (permuted cols)
// MODE 1: bias epilogue, out transposed [NB][DM][SEQ] bf16
// MODE 2: scores: X=Q, W=K (per batch), out = packed causal tiles fp16 raw
template <int MODE>
__global__ __launch_bounds__(256, 3) void gemm_proj(
    const unsigned short* __restrict__ Xin,
    const unsigned short* __restrict__ Win,
    const float* __restrict__ bias,
    const float* __restrict__ cosT, const float* __restrict__ sinT,
    unsigned short* __restrict__ out, int b0)
{
  __shared__ unsigned short As[128 * 32];
  __shared__ unsigned short Bs[128 * 32];
  const int tid = threadIdx.x, wid = tid >> 6, lane = tid & 63;
  const int c = lane & 15, g = lane >> 4;
  const int wm = wid >> 1, wn = wid & 1;

  const unsigned short* X;
  const unsigned short* W;
  int bm, bn;
  size_t tile_off = 0;
  if (MODE == 2) {
    // XCD-chunked swizzle: 528 tiles, 66 contiguous (tm-major) per XCD ->
    // Q row-panels shared within one XCD L2.
    int p = blockIdx.x;
    int idx = (p & 7) * (TRI / 8) + (p >> 3);
    int tm = (int)((sqrtf(8.0f * (float)idx + 1.0f) - 1.0f) * 0.5f);
    while (tri(tm + 1) <= idx) ++tm;
    while (tri(tm) > idx) --tm;
    int tn = idx - tri(tm);
    int b = b0 + blockIdx.y;
    bm = tm * 128; bn = tn * 128;
    X = Xin + (size_t)b * SEQ * DM;
    W = Win + (size_t)b * SEQ * DM;
    tile_off = ((size_t)blockIdx.y * TRI + idx) * 16384;
  } else {
    bm = blockIdx.y * 128; bn = blockIdx.x * 128;
    X = Xin; W = Win;
  }

  f32x4 zero4 = {0.f, 0.f, 0.f, 0.f};
  f32x4 acc[4][4];
  for (int m = 0; m < 4; ++m) for (int n = 0; n < 4; ++n) acc[m][n] = zero4;

  for (int kt = 0; kt < 32; ++kt) {
    const int k0 = kt * 32;
    for (int i = 0; i < 2; ++i) {
      int ch = wid * 2 + i;
      int row = ch * 16 + (lane >> 2);
      int kk = (lane & 3) * 8;
      gload_lds16(X + (size_t)(bm + row) * DM + k0 + kk, (void*)(As + ch * 512));
      gload_lds16(W + (size_t)(bn + row) * DM + k0 + kk, (void*)(Bs + ch * 512));
    }
    __syncthreads();
    short8 a[4], b[4];
    for (int m = 0; m < 4; ++m)
      a[m] = *(const short8*)(As + (wm * 64 + m * 16 + c) * 32 + g * 8);
    for (int n = 0; n < 4; ++n)
      b[n] = *(const short8*)(Bs + (wn * 64 + n * 16 + c) * 32 + g * 8);
    for (int m = 0; m < 4; ++m)
      for (int n = 0; n < 4; ++n)
        acc[m][n] = mfma16(a[m], b[n], acc[m][n]);
    __syncthreads();
  }

  if (MODE == 0) {
    for (int m = 0; m < 4; ++m) {
      int row0 = bm + wm * 64 + m * 16 + g * 4;
      for (int fp = 0; fp < 4; fp += 2) {
        int f_g = (bn >> 4) + wn * 4 + fp;
        float b0f = bias[f_g * 16 + c];
        float b1f = bias[(f_g + 1) * 16 + c];
        int j = (f_g >> 1) * 16 + c;
        for (int r = 0; r < 4; ++r) {
          int rowg = row0 + r;
          int s = rowg & (SEQ - 1);
          float x0 = acc[m][fp][r] + b0f;
          float x1 = acc[m][fp + 1][r] + b1f;
          float cv = cosT[(size_t)s * (DM / 2) + j];
          float sv = sinT[(size_t)s * (DM / 2) + j];
          out[(size_t)rowg * DM + f_g * 16 + c]       = f2bf(x0 * cv - x1 * sv);
          out[(size_t)rowg * DM + (f_g + 1) * 16 + c] = f2bf(x0 * sv + x1 * cv);
        }
      }
    }
  } else if (MODE == 1) {
    for (int m = 0; m < 4; ++m) {
      int s0 = bm + wm * 64 + m * 16 + g * 4;
      int bb = s0 >> 12;
      int sl = s0 & (SEQ - 1);
      for (int f = 0; f < 4; ++f) {
        int v = bn + wn * 64 + f * 16 + c;
        float bv_ = bias[v];
        ushort4v pk;
        for (int r = 0; r < 4; ++r) pk[r] = f2bf(acc[m][f][r] + bv_);
        *(ushort4v*)(out + ((size_t)(bb * DM + v)) * SEQ + sl) = pk;
      }
    }
  } else {
    unsigned short* tb = out + tile_off;
    for (int m = 0; m < 4; ++m) {
      int row0 = wm * 64 + m * 16 + g * 4;
      for (int n = 0; n < 4; ++n) {
        int col = wn * 64 + n * 16 + c;
        for (int r = 0; r < 4; ++r) {
          union { _Float16 h; unsigned short u; } cv;
          cv.h = (_Float16)acc[m][n][r];
          tb[(size_t)(row0 + r) * 128 + col] = cv.u;
        }
      }
    }
  }
}

// ---------------- row softmax over packed causal tiles (in place) ----------------
__global__ __launch_bounds__(256) void softmax_kernel(unsigned short* __restrict__ S_)
{
  const int tid = threadIdx.x, wid = tid >> 6, lane = tid & 63;
  const int widx = blockIdx.x * 4 + wid;
  const int li = widx >> 12;           // group-local batch
  const int r = widx & (SEQ - 1);
  unsigned short* Pb = S_ + (size_t)li * TRI * 16384;
  const int tmr = r >> 7, rr = r & 127;
  const float K2 = 0.04508422002778011f;  // (1/32) * log2(e)

  float v0[32], v1[32];
  float mx = -3.0e38f;
  #pragma unroll
  for (int tn = 0; tn < 32; ++tn) {
    if (tn <= tmr) {
      unsigned u = *(const unsigned*)(Pb + ((size_t)(tri(tmr) + tn)) * 16384 + rr * 128 + lane * 2);
      union { unsigned u; _Float16 h[2]; } cv; cv.u = u;
      int col = tn * 128 + lane * 2;
      float a0 = (col     <= r) ? (float)cv.h[0] : -3.0e38f;
      float a1 = (col + 1 <= r) ? (float)cv.h[1] : -3.0e38f;
      v0[tn] = a0; v1[tn] = a1;
      mx = fmaxf(mx, fmaxf(a0, a1));
    }
  }
  #pragma unroll
  for (int d = 1; d < 64; d <<= 1) mx = fmaxf(mx, __shfl_xor(mx, d, 64));
  float sum = 0.f;
  #pragma unroll
  for (int tn = 0; tn < 32; ++tn) {
    if (tn <= tmr) {
      float p0 = (v0[tn] < -1.0e37f) ? 0.f : exp2f((v0[tn] - mx) * K2);
      float p1 = (v1[tn] < -1.0e37f) ? 0.f : exp2f((v1[tn] - mx) * K2);
      v0[tn] = p0; v1[tn] = p1;
      sum += p0 + p1;
    }
  }
  #pragma unroll
  for (int d = 1; d < 64; d <<= 1) sum += __shfl_xor(sum, d, 64);
  float inv = 1.0f / sum;
  #pragma unroll
  for (int tn = 0; tn < 32; ++tn) {
    if (tn <= tmr) {
      unsigned o = (unsigned)f2bf(v0[tn] * inv) | ((unsigned)f2bf(v1[tn] * inv) << 16);
      *(unsigned*)(Pb + ((size_t)(tri(tmr) + tn)) * 16384 + rr * 128 + lane * 2) = o;
    }
  }
}

// ---------------- PV GEMM: z = P * V (V^T stored) ----------------
// Un-paired: one q-tile x one 128-col V slice per block -> 256*G blocks.
// Swizzle: XCD-chunked (P panels stay in one XCD L2) + big/small alternation
// j=(local+li)&3 so any aligned run of 4 same-XCD blocks sums to 132 K-steps.
__global__ __launch_bounds__(256, 4) void gemm_pv(
    const unsigned short* __restrict__ P,
    const unsigned short* __restrict__ Vt,
    float* __restrict__ z, int b0, int G)
{
  __shared__ unsigned short As[128 * 32];
  __shared__ unsigned short Bs[128 * 32];
  const int tid = threadIdx.x, wid = tid >> 6, lane = tid & 63;
  const int c = lane & 15, g = lane >> 4;
  const int wm = wid >> 1, wn = wid & 1;

  const int p = blockIdx.x;            // 0 .. 256*G-1
  const int x = p & 7;                 // XCD
  const int cpx = 32 * G;
  const int local = x * cpx + (p >> 3) - x * cpx;  // == p>>3 within chunk
  const int loc = p >> 3;              // [0, 32*G) position within XCD chunk
  const int li  = loc >> 5;            // group-local batch
  const int rem = loc & 31;
  const int n_  = (rem >> 2) & 7;
  const int j   = (rem + li) & 3;
  const int tm  = (j == 0) ? 31 - 2 * x :
                  (j == 1) ? 2 * x :
                  (j == 2) ? 30 - 2 * x : 2 * x + 1;
  (void)local;
  const int b = b0 + li;
  const unsigned short* Pb = P + (size_t)li * TRI * 16384;
  const int bn = n_ * 128;
  const int bm = tm * 128;

  f32x4 zero4 = {0.f, 0.f, 0.f, 0.f};
  f32x4 acc[4][4];
  for (int m = 0; m < 4; ++m) for (int n = 0; n < 4; ++n) acc[m][n] = zero4;

  const int nkt = (tm + 1) * 4;
  const size_t tribase = (size_t)tri(tm) * 16384;
  for (int kt = 0; kt < nkt; ++kt) {
    const int k0 = kt * 32;
    const int tk = k0 >> 7, off = k0 & 127;
    const unsigned short* Abase = Pb + tribase + (size_t)tk * 16384 + off;
    for (int i = 0; i < 2; ++i) {
      int ch = wid * 2 + i;
      int row = ch * 16 + (lane >> 2);
      int kk = (lane & 3) * 8;
      gload_lds16(Abase + row * 128 + kk, (void*)(As + ch * 512));
      gload_lds16(Vt + ((size_t)(b * DM + bn + row)) * SEQ + k0 + kk, (void*)(Bs + ch * 512));
    }
    __syncthreads();
    short8 a[4], bb[4];
    for (int m = 0; m < 4; ++m)
      a[m] = *(const short8*)(As + (wm * 64 + m * 16 + c) * 32 + g * 8);
    for (int n = 0; n < 4; ++n)
      bb[n] = *(const short8*)(Bs + (wn * 64 + n * 16 + c) * 32 + g * 8);
    for (int m = 0; m < 4; ++m)
      for (int n = 0; n < 4; ++n)
        acc[m][n] = mfma16(a[m], bb[n], acc[m][n]);
    __syncthreads();
  }

  for (int m = 0; m < 4; ++m) {
    int row0 = bm + wm * 64 + m * 16 + g * 4;
    for (int n = 0; n < 4; ++n) {
      int col = bn + wn * 64 + n * 16 + c;
      for (int r = 0; r < 4; ++r)
        z[((size_t)(b * SEQ + row0 + r)) * DM + col] = acc[m][n][r];
    }
  }
}

extern "C" void kernel_launch(void* const* d_in, const int* in_sizes, int n_in,
                              void* d_out, int out_size, void* d_ws, size_t ws_size,
                              hipStream_t stream) {
  const float* x    = (const float*)d_in[0];
  const float* cosT = (const float*)d_in[1];
  const float* sinT = (const float*)d_in[2];
  const float* Wq   = (const float*)d_in[3];
  const float* bq   = (const float*)d_in[4];
  const float* Wk   = (const float*)d_in[5];
  const float* bk   = (const float*)d_in[6];
  const float* Wv   = (const float*)d_in[7];
  const float* bv   = (const float*)d_in[8];
  float* z = (float*)d_out;

  char* ws = (char*)d_ws;
  unsigned short* xbf = (unsigned short*)(ws);
  unsigned short* Wqp = (unsigned short*)(ws + 33554432);
  unsigned short* Wkp = (unsigned short*)(ws + 35651584);
  unsigned short* Wvp = (unsigned short*)(ws + 37748736);
  float* bqp = (float*)(ws + 39845888);
  float* bkp = (float*)(ws + 39849984);
  float* bvp = (float*)(ws + 39854080);
  unsigned short* Qbf = (unsigned short*)(ws + 39858176);
  unsigned short* Kbf = (unsigned short*)(ws + 73412608);
  unsigned short* Vtb = (unsigned short*)(ws + 106967040);
  const size_t BASE = 140521472ULL;
  const size_t PER  = 17301504ULL;   // one batch of packed causal tiles
  unsigned short* Sc = (unsigned short*)(ws + BASE);

  int G = 1;
  if (ws_size >= BASE + 4 * PER)      G = 4;
  else if (ws_size >= BASE + 2 * PER) G = 2;

  convert_kernel<<<dim3(2048), dim3(256), 0, stream>>>(
      x, Wq, Wk, Wv, bq, bk, bv, xbf, Wqp, Wkp, Wvp, bqp, bkp, bvp);

  dim3 gg(8, 128);
  gemm_proj<0><<<gg, dim3(256), 0, stream>>>(xbf, Wqp, bqp, cosT, sinT, Qbf, 0);
  gemm_proj<0><<<gg, dim3(256), 0, stream>>>(xbf, Wkp, bkp, cosT, sinT, Kbf, 0);
  gemm_proj<1><<<gg, dim3(256), 0, stream>>>(xbf, Wvp, bvp, cosT, sinT, Vtb, 0);

  for (int b0 = 0; b0 < NB; b0 += G) {
    gemm_proj<2><<<dim3(TRI, G), dim3(256), 0, stream>>>(Qbf, Kbf, nullptr, nullptr, nullptr, Sc, b0);
    softmax_kernel<<<dim3(1024 * G), dim3(256), 0, stream>>>(Sc);
    gemm_pv<<<dim3(256 * G), dim3(256), 0, stream>>>(Sc, Vtb, z, b0, G);
  }
}

// Round 4
// 410.531 us; speedup vs baseline: 2.9203x; 1.0323x over previous
//
#include <hip/hip_runtime.h>
#include <cstdint>
#include <cstddef>

using short8   = __attribute__((ext_vector_type(8))) short;
using f32x4    = __attribute__((ext_vector_type(4))) float;
using ushort4v = __attribute__((ext_vector_type(4))) unsigned short;

#define DEV static __device__ __forceinline__

constexpr int NB  = 4;
constexpr int SEQ = 4096;
constexpr int DM  = 1024;
constexpr int BSR = NB * SEQ;            // 16384 flattened rows
constexpr size_t PBSTR = 136ULL * 65536; // per-batch panel elems (fp16/bf16)

DEV unsigned short f2bf(float f) {
  union { float f; unsigned u; } v; v.f = f;
  unsigned r = v.u + 0x7FFFu + ((v.u >> 16) & 1u);  // RNE
  return (unsigned short)(r >> 16);
}

DEV int tri(int t) { return t * (t + 1) / 2; }

DEV void gload_lds16(const void* g, void* l) {
  __builtin_amdgcn_global_load_lds(
      (__attribute__((address_space(1))) void*)(g),
      (__attribute__((address_space(3))) void*)(l), 16, 0, 0);
}

DEV f32x4 mfma16(short8 a, short8 b, f32x4 c) {
  return __builtin_amdgcn_mfma_f32_16x16x32_bf16(a, b, c, 0, 0, 0);
}

template <int N> DEV void waitvm() {
  static_assert(N == 8 || N == 10, "unsupported vmcnt");
  if constexpr (N == 8)  asm volatile("s_waitcnt vmcnt(8)" ::: "memory");
  if constexpr (N == 10) asm volatile("s_waitcnt vmcnt(10)" ::: "memory");
}
DEV void bar() { asm volatile("s_barrier" ::: "memory"); }

// RoPE-pair permutation: orig row index for permuted position p.
DEV int orig_row(int p) {
  int gI = p >> 5, rr = p & 31;
  return (rr < 16) ? (gI * 16 + rr) : (512 + gI * 16 + (rr - 16));
}

// ---------------- conversion / permutation ----------------
__global__ __launch_bounds__(256) void convert_kernel(
    const float* __restrict__ x,
    const float* __restrict__ Wq, const float* __restrict__ Wk, const float* __restrict__ Wv,
    const float* __restrict__ bq, const float* __restrict__ bk, const float* __restrict__ bv,
    unsigned short* __restrict__ xbf,
    unsigned short* __restrict__ Wqp, unsigned short* __restrict__ Wkp, unsigned short* __restrict__ Wvp,
    float* __restrict__ bqp, float* __restrict__ bkp, float* __restrict__ bvp)
{
  const int U1 = BSR * DM / 8;
  const int U2 = 2 * DM * DM / 8;
  const int U3 = DM * DM / 8;
  const int U4 = 3 * DM / 8;
  const int total = U1 + U2 + U3 + U4;
  for (int u = blockIdx.x * blockDim.x + threadIdx.x; u < total;
       u += gridDim.x * blockDim.x) {
    if (u < U1) {
      int e = u * 8;
      float4 f0 = ((const float4*)(x + e))[0];
      float4 f1 = ((const float4*)(x + e))[1];
      short8 o;
      o[0]=(short)f2bf(f0.x); o[1]=(short)f2bf(f0.y); o[2]=(short)f2bf(f0.z); o[3]=(short)f2bf(f0.w);
      o[4]=(short)f2bf(f1.x); o[5]=(short)f2bf(f1.y); o[6]=(short)f2bf(f1.z); o[7]=(short)f2bf(f1.w);
      *(short8*)(xbf + e) = o;
    } else if (u < U1 + U2) {
      int w = u - U1;
      int which = w >> 17;
      int r = w & (131072 - 1);
      int p = r >> 7;
      int m8 = (r & 127) * 8;
      const float* src = (which ? Wk : Wq) + (size_t)orig_row(p) * DM + m8;
      unsigned short* dst = (which ? Wkp : Wqp) + (size_t)p * DM + m8;
      float4 f0 = ((const float4*)src)[0];
      float4 f1 = ((const float4*)src)[1];
      short8 o;
      o[0]=(short)f2bf(f0.x); o[1]=(short)f2bf(f0.y); o[2]=(short)f2bf(f0.z); o[3]=(short)f2bf(f0.w);
      o[4]=(short)f2bf(f1.x); o[5]=(short)f2bf(f1.y); o[6]=(short)f2bf(f1.z); o[7]=(short)f2bf(f1.w);
      *(short8*)dst = o;
    } else if (u < U1 + U2 + U3) {
      int r = u - (U1 + U2);
      int p = r >> 7;
      int m8 = (r & 127) * 8;
      const float* src = Wv + (size_t)p * DM + m8;
      float4 f0 = ((const float4*)src)[0];
      float4 f1 = ((const float4*)src)[1];
      short8 o;
      o[0]=(short)f2bf(f0.x); o[1]=(short)f2bf(f0.y); o[2]=(short)f2bf(f0.z); o[3]=(short)f2bf(f0.w);
      o[4]=(short)f2bf(f1.x); o[5]=(short)f2bf(f1.y); o[6]=(short)f2bf(f1.z); o[7]=(short)f2bf(f1.w);
      *(short8*)(Wvp + (size_t)p * DM + m8) = o;
    } else {
      int t = u - (U1 + U2 + U3);
      int which = t >> 7;
      int i0 = (t & 127) * 8;
      for (int e = 0; e < 8; ++e) {
        int p = i0 + e;
        if (which == 0)      bqp[p] = bq[orig_row(p)];
        else if (which == 1) bkp[p] = bk[orig_row(p)];
        else                 bvp[p] = bv[p];
      }
    }
  }
}

// ---------------- deep-pipelined GEMM core ----------------
// 4 LDS buffers, BK=32, stage 3 K-tiles ahead, counted vmcnt (never 0),
// raw s_barrier x2 per tile, 2 MFMA phases with setprio, XOR-swizzled LDS.
template <int CN>
DEV void stage(const unsigned short* g, size_t ld, size_t k0,
               unsigned short* ldst, int sdst, int srow, int scg8) {
  #pragma unroll
  for (int cc = 0; cc < CN; ++cc)
    gload_lds16(g + (size_t)(cc * 128 + srow) * ld + k0 + scg8,
                (void*)(ldst + cc * 4096 + sdst));
}

template <int AROWS, int BROWS, int MF, int NF>
DEV void run_gemm(unsigned short* lds,
                  const unsigned short* __restrict__ Ag, size_t lda,
                  const unsigned short* __restrict__ Bg, size_t ldb,
                  int NT, int tid, int lane, int wm, int wn,
                  f32x4 (&acc)[MF][NF])
{
  constexpr int CA = AROWS / 128, CB = BROWS / 128;
  constexpr int VM = 2 * (CA + CB) + CA;   // outstanding loads newer than tile t
  constexpr int BUFE = (AROWS + BROWS) * 32;
  const int srow = tid >> 2;                       // 0..127
  const int scg8 = (((tid & 3) ^ (srow & 3))) * 8; // pre-swizzled src colgroup (elems)
  const int sdst = srow * 32 + (tid & 3) * 8;      // linear LDS dest (elems)
  const int c = lane & 15, g = lane >> 4;
  const int gsw = (g ^ (c & 3)) * 8;               // swizzled read colgroup (elems)
  int aoff[MF], boff[NF];
  #pragma unroll
  for (int f = 0; f < MF; ++f) aoff[f] = (wm * (MF * 16) + f * 16 + c) * 32 + gsw;
  #pragma unroll
  for (int f = 0; f < NF; ++f) boff[f] = AROWS * 32 + (wn * (NF * 16) + f * 16 + c) * 32 + gsw;

  // prologue: stage tiles 0,1,2 (NT >= 8 always)
  #pragma unroll
  for (int p = 0; p < 3; ++p) {
    stage<CA>(Ag, lda, (size_t)p * 32, lds + p * BUFE, sdst, srow, scg8);
    stage<CB>(Bg, ldb, (size_t)p * 32, lds + p * BUFE + AROWS * 32, sdst, srow, scg8);
  }

  for (int t = 0; t < NT; ++t) {
    const int bsel = t & 3, nsel = (t + 3) & 3;
    const int ts = (t + 3 < NT) ? (t + 3) : (NT - 1);  // dummy re-stage keeps vmcnt constant
    unsigned short* lb = lds + bsel * BUFE;
    // ---- phase A ----
    stage<CA>(Ag, lda, (size_t)ts * 32, lds + nsel * BUFE, sdst, srow, scg8);
    waitvm<VM>();
    bar();
    short8 av[MF / 2], bv[NF];
    #pragma unroll
    for (int f = 0; f < MF / 2; ++f) av[f] = *(const short8*)(lb + aoff[f]);
    #pragma unroll
    for (int f = 0; f < NF; ++f)     bv[f] = *(const short8*)(lb + boff[f]);
    __builtin_amdgcn_s_setprio(1);
    #pragma unroll
    for (int mf = 0; mf < MF / 2; ++mf)
      #pragma unroll
      for (int nf = 0; nf < NF; ++nf)
        acc[mf][nf] = mfma16(av[mf], bv[nf], acc[mf][nf]);
    __builtin_amdgcn_s_setprio(0);
    // ---- phase B ----
    stage<CB>(Bg, ldb, (size_t)ts * 32, lds + nsel * BUFE + AROWS * 32, sdst, srow, scg8);
    #pragma unroll
    for (int f = 0; f < MF / 2; ++f) av[f] = *(const short8*)(lb + aoff[MF / 2 + f]);
    __builtin_amdgcn_s_setprio(1);
    #pragma unroll
    for (int mf = 0; mf < MF / 2; ++mf)
      #pragma unroll
      for (int nf = 0; nf < NF; ++nf)
        acc[MF / 2 + mf][nf] = mfma16(av[mf], bv[nf], acc[MF / 2 + mf][nf]);
    __builtin_amdgcn_s_setprio(0);
    __builtin_amdgcn_sched_barrier(0);  // pin MFMAs before the barrier
    bar();
  }
  asm volatile("s_waitcnt vmcnt(0)" ::: "memory");
}

// ---------------- 256x256 GEMM kernels ----------------
// MODE 0: rope epilogue -> [BSR][DM] bf16 (permuted cols)
// MODE 1: bias epilogue -> transposed [NB][DM][SEQ] bf16
// MODE 2: scores -> per-256-row causal panels, raw fp16
template <int MODE>
__global__ __launch_bounds__(512, 2) void k_gemm256(
    const unsigned short* __restrict__ Ain,
    const unsigned short* __restrict__ Bin,
    const float* __restrict__ bias,
    const float* __restrict__ cosT, const float* __restrict__ sinT,
    unsigned short* __restrict__ out, int b0, int G)
{
  __shared__ unsigned short lds[4 * 16384];  // 128 KiB
  const int tid = threadIdx.x, lane = tid & 63, wid = tid >> 6;
  const int wm = wid >> 2, wn = wid & 3;     // 2 x 4 waves
  const int c = lane & 15, g = lane >> 4;

  const unsigned short* Ag;
  const unsigned short* Bg;
  int bm, bn, tm = 0, li = 0;
  if (MODE == 2) {
    int lin = (blockIdx.x & 7) * (17 * G) + (blockIdx.x >> 3);
    li = lin / 136;
    int t136 = lin - li * 136;
    tm = (int)((sqrtf(8.0f * (float)t136 + 1.0f) - 1.0f) * 0.5f);
    while (tri(tm + 1) <= t136) ++tm;
    while (tri(tm) > t136) --tm;
    int tn = t136 - tri(tm);
    int b = b0 + li;
    bm = tm * 256; bn = tn * 256;
    Ag = Ain + ((size_t)b * SEQ + bm) * DM;
    Bg = Bin + ((size_t)b * SEQ + bn) * DM;
  } else {
    int xcd = blockIdx.x & 7, idx = blockIdx.x >> 3;
    bm = (xcd * 8 + (idx >> 2)) * 256;
    bn = (idx & 3) * 256;
    Ag = Ain + (size_t)bm * DM;
    Bg = Bin + (size_t)bn * DM;
  }

  f32x4 z4 = {0.f, 0.f, 0.f, 0.f};
  f32x4 acc[8][4];
  #pragma unroll
  for (int m = 0; m < 8; ++m)
    #pragma unroll
    for (int n = 0; n < 4; ++n) acc[m][n] = z4;

  run_gemm<256, 256, 8, 4>(lds, Ag, DM, Bg, DM, 32, tid, lane, wm, wn, acc);

  if (MODE == 0) {
    #pragma unroll
    for (int am = 0; am < 8; ++am) {
      int row0 = bm + wm * 128 + am * 16 + g * 4;
      #pragma unroll
      for (int fp = 0; fp < 4; fp += 2) {
        int f_g = (bn >> 4) + wn * 4 + fp;
        float b0f = bias[f_g * 16 + c];
        float b1f = bias[f_g * 16 + 16 + c];
        int j = (f_g >> 1) * 16 + c;
        #pragma unroll
        for (int r = 0; r < 4; ++r) {
          int rowg = row0 + r;
          int s = rowg & (SEQ - 1);
          float x0 = acc[am][fp][r] + b0f;
          float x1 = acc[am][fp + 1][r] + b1f;
          float cv = cosT[(size_t)s * (DM / 2) + j];
          float sv = sinT[(size_t)s * (DM / 2) + j];
          out[(size_t)rowg * DM + f_g * 16 + c]      = f2bf(x0 * cv - x1 * sv);
          out[(size_t)rowg * DM + f_g * 16 + 16 + c] = f2bf(x0 * sv + x1 * cv);
        }
      }
    }
  } else if (MODE == 1) {
    #pragma unroll
    for (int am = 0; am < 8; ++am) {
      int s0 = bm + wm * 128 + am * 16 + g * 4;
      int bb = s0 >> 12;
      int sl = s0 & (SEQ - 1);
      #pragma unroll
      for (int fn = 0; fn < 4; ++fn) {
        int v = bn + wn * 64 + fn * 16 + c;
        float bv_ = bias[v];
        ushort4v pk;
        #pragma unroll
        for (int r = 0; r < 4; ++r) pk[r] = f2bf(acc[am][fn][r] + bv_);
        *(ushort4v*)(out + ((size_t)(bb * DM + v)) * SEQ + sl) = pk;
      }
    }
  } else {
    const size_t Kp = (size_t)(tm + 1) * 256;
    unsigned short* pb = out + (size_t)li * PBSTR + (size_t)tri(tm) * 65536;
    #pragma unroll
    for (int am = 0; am < 8; ++am) {
      int lrow = wm * 128 + am * 16 + g * 4;
      #pragma unroll
      for (int fn = 0; fn < 4; ++fn) {
        int col = (bn & 255) + wn * 64 + fn * 16 + c;  // bn within panel
        #pragma unroll
        for (int r = 0; r < 4; ++r) {
          union { _Float16 h; unsigned short u; } cv;
          cv.h = (_Float16)acc[am][fn][r];
          pb[(size_t)(lrow + r) * Kp + (bn - ((bn >> 8) << 8)) + 0] = cv.u;  // placeholder avoided below
        }
      }
    }
  }
}

// NOTE: MODE 2 epilogue above is replaced by a corrected explicit version:
// (kept separate to avoid the placeholder arithmetic confusion)
template <>
__global__ __launch_bounds__(512, 2) void k_gemm256<3>(
    const unsigned short* __restrict__ Ain,
    const unsigned short* __restrict__ Bin,
    const float* __restrict__ bias,
    const float* __restrict__ cosT, const float* __restrict__ sinT,
    unsigned short* __restrict__ out, int b0, int G)
{
  __shared__ unsigned short lds[4 * 16384];
  const int tid = threadIdx.x, lane = tid & 63, wid = tid >> 6;
  const int wm = wid >> 2, wn = wid & 3;
  const int c = lane & 15, g = lane >> 4;

  int lin = (blockIdx.x & 7) * (17 * G) + (blockIdx.x >> 3);
  int li = lin / 136;
  int t136 = lin - li * 136;
  int tm = (int)((sqrtf(8.0f * (float)t136 + 1.0f) - 1.0f) * 0.5f);
  while (tri(tm + 1) <= t136) ++tm;
  while (tri(tm) > t136) --tm;
  int tn = t136 - tri(tm);
  int b = b0 + li;
  const int bm = tm * 256, bn = tn * 256;
  const unsigned short* Ag = Ain + ((size_t)b * SEQ + bm) * DM;
  const unsigned short* Bg = Bin + ((size_t)b * SEQ + bn) * DM;

  f32x4 z4 = {0.f, 0.f, 0.f, 0.f};
  f32x4 acc[8][4];
  #pragma unroll
  for (int m = 0; m < 8; ++m)
    #pragma unroll
    for (int n = 0; n < 4; ++n) acc[m][n] = z4;

  run_gemm<256, 256, 8, 4>(lds, Ag, DM, Bg, DM, 32, tid, lane, wm, wn, acc);

  const size_t Kp = (size_t)(tm + 1) * 256;
  unsigned short* pb = out + (size_t)li * PBSTR + (size_t)tri(tm) * 65536;
  #pragma unroll
  for (int am = 0; am < 8; ++am) {
    int lrow = wm * 128 + am * 16 + g * 4;
    #pragma unroll
    for (int fn = 0; fn < 4; ++fn) {
      int col = bn + wn * 64 + fn * 16 + c;   // global col < Kp
      #pragma unroll
      for (int r = 0; r < 4; ++r) {
        union { _Float16 h; unsigned short u; } cv;
        cv.h = (_Float16)acc[am][fn][r];
        pb[(size_t)(lrow + r) * Kp + col] = cv.u;
      }
    }
  }
}

// ---------------- row softmax over panels (in place) ----------------
__global__ __launch_bounds__(256) void softmax_panel(unsigned short* __restrict__ S_)
{
  const int tid = threadIdx.x, wid = tid >> 6, lane = tid & 63;
  const int widx = blockIdx.x * 4 + wid;
  const int li = widx >> 12;
  const int r = widx & (SEQ - 1);
  const int p = r >> 8;
  const size_t Kp = (size_t)(p + 1) * 256;
  const int nt = (p + 1) * 2;               // 128-col chunks
  unsigned short* base = S_ + (size_t)li * PBSTR + (size_t)tri(p) * 65536 +
                         (size_t)(r & 255) * Kp;
  const float K2 = 0.04508422002778011f;    // (1/32) * log2(e)

  float v0[32], v1[32];
  float mx = -3.0e38f;
  #pragma unroll
  for (int tn = 0; tn < 32; ++tn) {
    if (tn < nt) {
      unsigned u = *(const unsigned*)(base + tn * 128 + lane * 2);
      union { unsigned u; _Float16 h[2]; } cv; cv.u = u;
      int col = tn * 128 + lane * 2;
      float a0 = (col     <= r) ? (float)cv.h[0] : -3.0e38f;
      float a1 = (col + 1 <= r) ? (float)cv.h[1] : -3.0e38f;
      v0[tn] = a0; v1[tn] = a1;
      mx = fmaxf(mx, fmaxf(a0, a1));
    }
  }
  #pragma unroll
  for (int d = 1; d < 64; d <<= 1) mx = fmaxf(mx, __shfl_xor(mx, d, 64));
  float sum = 0.f;
  #pragma unroll
  for (int tn = 0; tn < 32; ++tn) {
    if (tn < nt) {
      float p0 = (v0[tn] < -1.0e37f) ? 0.f : exp2f((v0[tn] - mx) * K2);
      float p1 = (v1[tn] < -1.0e37f) ? 0.f : exp2f((v1[tn] - mx) * K2);
      v0[tn] = p0; v1[tn] = p1;
      sum += p0 + p1;
    }
  }
  #pragma unroll
  for (int d = 1; d < 64; d <<= 1) sum += __shfl_xor(sum, d, 64);
  float inv = 1.0f / sum;
  #pragma unroll
  for (int tn = 0; tn < 32; ++tn) {
    if (tn < nt) {
      unsigned o = (unsigned)f2bf(v0[tn] * inv) | ((unsigned)f2bf(v1[tn] * inv) << 16);
      *(unsigned*)(base + tn * 128 + lane * 2) = o;
    }
  }
}

// ---------------- PV GEMM: z = P * V (panel A, Vt B) ----------------
// BM=256 (one panel), BN=128; 8 waves 4x2; paired panels (p, 15-p) per block.
__global__ __launch_bounds__(512, 2) void k_pv(
    const unsigned short* __restrict__ P,
    const unsigned short* __restrict__ Vt,
    float* __restrict__ z, int b0, int G)
{
  __shared__ unsigned short lds[4 * 12288];  // 96 KiB
  const int tid = threadIdx.x, lane = tid & 63, wid = tid >> 6;
  const int wm = wid >> 1, wn = wid & 1;     // 4 x 2 waves
  const int c = lane & 15, g = lane >> 4;
  const int n8 = blockIdx.x & 7;
  const int s = blockIdx.x >> 3;
  const int li = s % G;
  const int pl = s / G;
  const int b = b0 + li;
  const unsigned short* Bg = Vt + ((size_t)b * DM + n8 * 128) * SEQ;

  for (int h = 0; h < 2; ++h) {
    const int p = h ? (15 - pl) : pl;
    const int NT = (p + 1) * 8;
    const size_t Kp = (size_t)(p + 1) * 256;
    const unsigned short* panel = P + (size_t)li * PBSTR + (size_t)tri(p) * 65536;

    f32x4 z4 = {0.f, 0.f, 0.f, 0.f};
    f32x4 acc[4][4];
    #pragma unroll
    for (int m = 0; m < 4; ++m)
      #pragma unroll
      for (int n = 0; n < 4; ++n) acc[m][n] = z4;

    run_gemm<256, 128, 4, 4>(lds, panel, Kp, Bg, SEQ, NT, tid, lane, wm, wn, acc);

    #pragma unroll
    for (int am = 0; am < 4; ++am) {
      int row = p * 256 + wm * 64 + am * 16 + g * 4;
      #pragma unroll
      for (int fn = 0; fn < 4; ++fn) {
        int col = n8 * 128 + wn * 64 + fn * 16 + c;
        #pragma unroll
        for (int r = 0; r < 4; ++r)
          z[((size_t)(b * SEQ + row + r)) * DM + col] = acc[am][fn][r];
      }
    }
    __syncthreads();  // full drain between paired jobs
  }
}

extern "C" void kernel_launch(void* const* d_in, const int* in_sizes, int n_in,
                              void* d_out, int out_size, void* d_ws, size_t ws_size,
                              hipStream_t stream) {
  const float* x    = (const float*)d_in[0];
  const float* cosT = (const float*)d_in[1];
  const float* sinT = (const float*)d_in[2];
  const float* Wq   = (const float*)d_in[3];
  const float* bq   = (const float*)d_in[4];
  const float* Wk   = (const float*)d_in[5];
  const float* bk   = (const float*)d_in[6];
  const float* Wv   = (const float*)d_in[7];
  const float* bv   = (const float*)d_in[8];
  float* z = (float*)d_out;

  char* ws = (char*)d_ws;
  unsigned short* xbf = (unsigned short*)(ws);
  unsigned short* Wqp = (unsigned short*)(ws + 33554432);
  unsigned short* Wkp = (unsigned short*)(ws + 35651584);
  unsigned short* Wvp = (unsigned short*)(ws + 37748736);
  float* bqp = (float*)(ws + 39845888);
  float* bkp = (float*)(ws + 39849984);
  float* bvp = (float*)(ws + 39854080);
  unsigned short* Qbf = (unsigned short*)(ws + 39858176);
  unsigned short* Kbf = (unsigned short*)(ws + 73412608);
  unsigned short* Vtb = (unsigned short*)(ws + 106967040);
  const size_t BASE = 140521472ULL;
  const size_t PER  = PBSTR * 2ULL;       // 17,825,792 B per batch of panels
  unsigned short* Sc = (unsigned short*)(ws + BASE);

  int G = 1;
  if (ws_size >= BASE + 4 * PER)      G = 4;
  else if (ws_size >= BASE + 2 * PER) G = 2;

  convert_kernel<<<dim3(2048), dim3(256), 0, stream>>>(
      x, Wq, Wk, Wv, bq, bk, bv, xbf, Wqp, Wkp, Wvp, bqp, bkp, bvp);

  k_gemm256<0><<<dim3(256), dim3(512), 0, stream>>>(xbf, Wqp, bqp, cosT, sinT, Qbf, 0, 1);
  k_gemm256<0><<<dim3(256), dim3(512), 0, stream>>>(xbf, Wkp, bkp, cosT, sinT, Kbf, 0, 1);
  k_gemm256<1><<<dim3(256), dim3(512), 0, stream>>>(xbf, Wvp, bvp, cosT, sinT, Vtb, 0, 1);

  for (int b0 = 0; b0 < NB; b0 += G) {
    k_gemm256<3><<<dim3(136 * G), dim3(512), 0, stream>>>(Qbf, Kbf, nullptr, nullptr, nullptr, Sc, b0, G);
    softmax_panel<<<dim3(1024 * G), dim3(256), 0, stream>>>(Sc);
    k_pv<<<dim3(64 * G), dim3(512), 0, stream>>>(Sc, Vtb, z, b0, G);
  }
}

// Round 5
// 371.356 us; speedup vs baseline: 3.2284x; 1.1055x over previous
//
#include <hip/hip_runtime.h>
#include <cstdint>
#include <cstddef>

using short8   = __attribute__((ext_vector_type(8))) short;
using f32x4    = __attribute__((ext_vector_type(4))) float;
using ushort4v = __attribute__((ext_vector_type(4))) unsigned short;

#define DEV static __device__ __forceinline__

constexpr int NB  = 4;
constexpr int SEQ = 4096;
constexpr int DM  = 1024;
constexpr int BSR = NB * SEQ;            // 16384 flattened rows
constexpr size_t PBSTR = 136ULL * 65536; // per-batch panel elems (fp16/bf16)

DEV unsigned short f2bf(float f) {
  union { float f; unsigned u; } v; v.f = f;
  unsigned r = v.u + 0x7FFFu + ((v.u >> 16) & 1u);  // RNE
  return (unsigned short)(r >> 16);
}

DEV int tri(int t) { return t * (t + 1) / 2; }

DEV void gload_lds16(const void* g, void* l) {
  __builtin_amdgcn_global_load_lds(
      (__attribute__((address_space(1))) void*)(g),
      (__attribute__((address_space(3))) void*)(l), 16, 0, 0);
}

DEV f32x4 mfma16(short8 a, short8 b, f32x4 c) {
  return __builtin_amdgcn_mfma_f32_16x16x32_bf16(a, b, c, 0, 0, 0);
}

template <int N> DEV void waitvm() {
  static_assert(N == 8 || N == 10, "unsupported vmcnt");
  if constexpr (N == 8)  asm volatile("s_waitcnt vmcnt(8)" ::: "memory");
  if constexpr (N == 10) asm volatile("s_waitcnt vmcnt(10)" ::: "memory");
}
DEV void bar() { asm volatile("s_barrier" ::: "memory"); }

// RoPE-pair permutation: orig row index for permuted position p.
DEV int orig_row(int p) {
  int gI = p >> 5, rr = p & 31;
  return (rr < 16) ? (gI * 16 + rr) : (512 + gI * 16 + (rr - 16));
}

// ---------------- conversion / permutation ----------------
__global__ __launch_bounds__(256) void convert_kernel(
    const float* __restrict__ x,
    const float* __restrict__ Wq, const float* __restrict__ Wk, const float* __restrict__ Wv,
    const float* __restrict__ bq, const float* __restrict__ bk, const float* __restrict__ bv,
    unsigned short* __restrict__ xbf,
    unsigned short* __restrict__ Wqp, unsigned short* __restrict__ Wkp, unsigned short* __restrict__ Wvp,
    float* __restrict__ bqp, float* __restrict__ bkp, float* __restrict__ bvp)
{
  const int U1 = BSR * DM / 8;
  const int U2 = 2 * DM * DM / 8;
  const int U3 = DM * DM / 8;
  const int U4 = 3 * DM / 8;
  const int total = U1 + U2 + U3 + U4;
  for (int u = blockIdx.x * blockDim.x + threadIdx.x; u < total;
       u += gridDim.x * blockDim.x) {
    if (u < U1) {
      int e = u * 8;
      float4 f0 = ((const float4*)(x + e))[0];
      float4 f1 = ((const float4*)(x + e))[1];
      short8 o;
      o[0]=(short)f2bf(f0.x); o[1]=(short)f2bf(f0.y); o[2]=(short)f2bf(f0.z); o[3]=(short)f2bf(f0.w);
      o[4]=(short)f2bf(f1.x); o[5]=(short)f2bf(f1.y); o[6]=(short)f2bf(f1.z); o[7]=(short)f2bf(f1.w);
      *(short8*)(xbf + e) = o;
    } else if (u < U1 + U2) {
      int w = u - U1;
      int which = w >> 17;
      int r = w & (131072 - 1);
      int p = r >> 7;
      int m8 = (r & 127) * 8;
      const float* src = (which ? Wk : Wq) + (size_t)orig_row(p) * DM + m8;
      unsigned short* dst = (which ? Wkp : Wqp) + (size_t)p * DM + m8;
      float4 f0 = ((const float4*)src)[0];
      float4 f1 = ((const float4*)src)[1];
      short8 o;
      o[0]=(short)f2bf(f0.x); o[1]=(short)f2bf(f0.y); o[2]=(short)f2bf(f0.z); o[3]=(short)f2bf(f0.w);
      o[4]=(short)f2bf(f1.x); o[5]=(short)f2bf(f1.y); o[6]=(short)f2bf(f1.z); o[7]=(short)f2bf(f1.w);
      *(short8*)dst = o;
    } else if (u < U1 + U2 + U3) {
      int r = u - (U1 + U2);
      int p = r >> 7;
      int m8 = (r & 127) * 8;
      const float* src = Wv + (size_t)p * DM + m8;
      float4 f0 = ((const float4*)src)[0];
      float4 f1 = ((const float4*)src)[1];
      short8 o;
      o[0]=(short)f2bf(f0.x); o[1]=(short)f2bf(f0.y); o[2]=(short)f2bf(f0.z); o[3]=(short)f2bf(f0.w);
      o[4]=(short)f2bf(f1.x); o[5]=(short)f2bf(f1.y); o[6]=(short)f2bf(f1.z); o[7]=(short)f2bf(f1.w);
      *(short8*)(Wvp + (size_t)p * DM + m8) = o;
    } else {
      int t = u - (U1 + U2 + U3);
      int which = t >> 7;
      int i0 = (t & 127) * 8;
      for (int e = 0; e < 8; ++e) {
        int p = i0 + e;
        if (which == 0)      bqp[p] = bq[orig_row(p)];
        else if (which == 1) bkp[p] = bk[orig_row(p)];
        else                 bvp[p] = bv[p];
      }
    }
  }
}

// ---------------- deep-pipelined GEMM core ----------------
// 4 LDS buffers, BK=32, stage 3 K-tiles ahead, counted vmcnt (never 0),
// raw s_barrier x2 per tile, 2 MFMA phases with setprio.
// LDS swizzle: colgroup ^= (row>>1)&3  (bank-quad = (4*row + cg)&7; same-parity
// rows distribute 2-2-2-2 over their 4 quads -> 2-way = free).
template <int CN>
DEV void stage(const unsigned short* g, size_t ld, size_t k0,
               unsigned short* ldst, int sdst, int srow, int scg8) {
  #pragma unroll
  for (int cc = 0; cc < CN; ++cc)
    gload_lds16(g + (size_t)(cc * 128 + srow) * ld + k0 + scg8,
                (void*)(ldst + cc * 4096 + sdst));
}

template <int AROWS, int BROWS, int MF, int NF>
DEV void run_gemm(unsigned short* lds,
                  const unsigned short* __restrict__ Ag, size_t lda,
                  const unsigned short* __restrict__ Bg, size_t ldb,
                  int NT, int tid, int lane, int wm, int wn,
                  f32x4 (&acc)[MF][NF])
{
  constexpr int CA = AROWS / 128, CB = BROWS / 128;
  constexpr int VM = 2 * (CA + CB) + CA;   // outstanding loads newer than tile t
  constexpr int BUFE = (AROWS + BROWS) * 32;
  const int srow = tid >> 2;                              // 0..127
  const int scg8 = (((tid & 3) ^ ((srow >> 1) & 3))) * 8; // pre-swizzled src colgroup
  const int sdst = srow * 32 + (tid & 3) * 8;             // linear LDS dest (elems)
  const int c = lane & 15, g = lane >> 4;
  const int gsw = (g ^ ((c >> 1) & 3)) * 8;               // swizzled read colgroup
  int aoff[MF], boff[NF];
  #pragma unroll
  for (int f = 0; f < MF; ++f) aoff[f] = (wm * (MF * 16) + f * 16 + c) * 32 + gsw;
  #pragma unroll
  for (int f = 0; f < NF; ++f) boff[f] = AROWS * 32 + (wn * (NF * 16) + f * 16 + c) * 32 + gsw;

  // prologue: stage tiles 0,1,2 (NT >= 8 always)
  #pragma unroll
  for (int p = 0; p < 3; ++p) {
    stage<CA>(Ag, lda, (size_t)p * 32, lds + p * BUFE, sdst, srow, scg8);
    stage<CB>(Bg, ldb, (size_t)p * 32, lds + p * BUFE + AROWS * 32, sdst, srow, scg8);
  }

  for (int t = 0; t < NT; ++t) {
    const int bsel = t & 3, nsel = (t + 3) & 3;
    const int ts = (t + 3 < NT) ? (t + 3) : (NT - 1);  // dummy re-stage keeps vmcnt constant
    unsigned short* lb = lds + bsel * BUFE;
    // ---- phase A ----
    stage<CA>(Ag, lda, (size_t)ts * 32, lds + nsel * BUFE, sdst, srow, scg8);
    waitvm<VM>();
    bar();
    short8 av[MF / 2], bv[NF];
    #pragma unroll
    for (int f = 0; f < MF / 2; ++f) av[f] = *(const short8*)(lb + aoff[f]);
    #pragma unroll
    for (int f = 0; f < NF; ++f)     bv[f] = *(const short8*)(lb + boff[f]);
    __builtin_amdgcn_s_setprio(1);
    #pragma unroll
    for (int mf = 0; mf < MF / 2; ++mf)
      #pragma unroll
      for (int nf = 0; nf < NF; ++nf)
        acc[mf][nf] = mfma16(av[mf], bv[nf], acc[mf][nf]);
    __builtin_amdgcn_s_setprio(0);
    // ---- phase B ----
    stage<CB>(Bg, ldb, (size_t)ts * 32, lds + nsel * BUFE + AROWS * 32, sdst, srow, scg8);
    #pragma unroll
    for (int f = 0; f < MF / 2; ++f) av[f] = *(const short8*)(lb + aoff[MF / 2 + f]);
    __builtin_amdgcn_s_setprio(1);
    #pragma unroll
    for (int mf = 0; mf < MF / 2; ++mf)
      #pragma unroll
      for (int nf = 0; nf < NF; ++nf)
        acc[MF / 2 + mf][nf] = mfma16(av[mf], bv[nf], acc[MF / 2 + mf][nf]);
    __builtin_amdgcn_s_setprio(0);
    __builtin_amdgcn_sched_barrier(0);  // pin MFMAs before the barrier
    bar();
  }
  asm volatile("s_waitcnt vmcnt(0)" ::: "memory");
}

// ---------------- 256x256 GEMM kernels ----------------
// MODE 0: rope epilogue -> [BSR][DM] bf16 (permuted cols)
// MODE 1: bias epilogue -> transposed [NB][DM][SEQ] bf16
// MODE 2: scores -> per-256-row causal panels, raw fp16
template <int MODE>
__global__ __launch_bounds__(512, 2) void k_gemm256(
    const unsigned short* __restrict__ Ain,
    const unsigned short* __restrict__ Bin,
    const float* __restrict__ bias,
    const float* __restrict__ cosT, const float* __restrict__ sinT,
    unsigned short* __restrict__ out, int b0, int G)
{
  __shared__ unsigned short lds[4 * 16384];  // 128 KiB
  const int tid = threadIdx.x, lane = tid & 63, wid = tid >> 6;
  const int wm = wid >> 2, wn = wid & 3;     // 2 x 4 waves
  const int c = lane & 15, g = lane >> 4;

  const unsigned short* Ag;
  const unsigned short* Bg;
  int bm, bn, tm = 0, li = 0;
  if (MODE == 2) {
    int lin = (blockIdx.x & 7) * (17 * G) + (blockIdx.x >> 3);
    li = lin / 136;
    int t136 = lin - li * 136;
    tm = (int)((sqrtf(8.0f * (float)t136 + 1.0f) - 1.0f) * 0.5f);
    while (tri(tm + 1) <= t136) ++tm;
    while (tri(tm) > t136) --tm;
    int tn = t136 - tri(tm);
    int b = b0 + li;
    bm = tm * 256; bn = tn * 256;
    Ag = Ain + ((size_t)b * SEQ + bm) * DM;
    Bg = Bin + ((size_t)b * SEQ + bn) * DM;
  } else {
    int xcd = blockIdx.x & 7, idx = blockIdx.x >> 3;
    bm = (xcd * 8 + (idx >> 2)) * 256;
    bn = (idx & 3) * 256;
    Ag = Ain + (size_t)bm * DM;
    Bg = Bin + (size_t)bn * DM;
  }

  f32x4 z4 = {0.f, 0.f, 0.f, 0.f};
  f32x4 acc[8][4];
  #pragma unroll
  for (int m = 0; m < 8; ++m)
    #pragma unroll
    for (int n = 0; n < 4; ++n) acc[m][n] = z4;

  run_gemm<256, 256, 8, 4>(lds, Ag, DM, Bg, DM, 32, tid, lane, wm, wn, acc);

  if (MODE == 0) {
    #pragma unroll
    for (int am = 0; am < 8; ++am) {
      int row0 = bm + wm * 128 + am * 16 + g * 4;
      #pragma unroll
      for (int fp = 0; fp < 4; fp += 2) {
        int f_g = (bn >> 4) + wn * 4 + fp;
        float b0f = bias[f_g * 16 + c];
        float b1f = bias[f_g * 16 + 16 + c];
        int j = (f_g >> 1) * 16 + c;
        #pragma unroll
        for (int r = 0; r < 4; ++r) {
          int rowg = row0 + r;
          int s = rowg & (SEQ - 1);
          float x0 = acc[am][fp][r] + b0f;
          float x1 = acc[am][fp + 1][r] + b1f;
          float cv = cosT[(size_t)s * (DM / 2) + j];
          float sv = sinT[(size_t)s * (DM / 2) + j];
          out[(size_t)rowg * DM + f_g * 16 + c]      = f2bf(x0 * cv - x1 * sv);
          out[(size_t)rowg * DM + f_g * 16 + 16 + c] = f2bf(x0 * sv + x1 * cv);
        }
      }
    }
  } else if (MODE == 1) {
    #pragma unroll
    for (int am = 0; am < 8; ++am) {
      int s0 = bm + wm * 128 + am * 16 + g * 4;
      int bb = s0 >> 12;
      int sl = s0 & (SEQ - 1);
      #pragma unroll
      for (int fn = 0; fn < 4; ++fn) {
        int v = bn + wn * 64 + fn * 16 + c;
        float bv_ = bias[v];
        ushort4v pk;
        #pragma unroll
        for (int r = 0; r < 4; ++r) pk[r] = f2bf(acc[am][fn][r] + bv_);
        *(ushort4v*)(out + ((size_t)(bb * DM + v)) * SEQ + sl) = pk;
      }
    }
  } else {
    const size_t Kp = (size_t)(tm + 1) * 256;
    unsigned short* pb = out + (size_t)li * PBSTR + (size_t)tri(tm) * 65536;
    #pragma unroll
    for (int am = 0; am < 8; ++am) {
      int lrow = wm * 128 + am * 16 + g * 4;
      #pragma unroll
      for (int fn = 0; fn < 4; ++fn) {
        int col = bn + wn * 64 + fn * 16 + c;   // global col < Kp
        #pragma unroll
        for (int r = 0; r < 4; ++r) {
          union { _Float16 h; unsigned short u; } cv;
          cv.h = (_Float16)acc[am][fn][r];
          pb[(size_t)(lrow + r) * Kp + col] = cv.u;
        }
      }
    }
  }
}

// ---------------- row softmax over panels (in place) ----------------
__global__ __launch_bounds__(256) void softmax_panel(unsigned short* __restrict__ S_)
{
  const int tid = threadIdx.x, wid = tid >> 6, lane = tid & 63;
  const int widx = blockIdx.x * 4 + wid;
  const int li = widx >> 12;
  const int r = widx & (SEQ - 1);
  const int p = r >> 8;
  const size_t Kp = (size_t)(p + 1) * 256;
  const int nt = (p + 1) * 2;               // 128-col chunks
  unsigned short* base = S_ + (size_t)li * PBSTR + (size_t)tri(p) * 65536 +
                         (size_t)(r & 255) * Kp;
  const float K2 = 0.04508422002778011f;    // (1/32) * log2(e)

  float v0[32], v1[32];
  float mx = -3.0e38f;
  #pragma unroll
  for (int tn = 0; tn < 32; ++tn) {
    if (tn < nt) {
      unsigned u = *(const unsigned*)(base + tn * 128 + lane * 2);
      union { unsigned u; _Float16 h[2]; } cv; cv.u = u;
      int col = tn * 128 + lane * 2;
      float a0 = (col     <= r) ? (float)cv.h[0] : -3.0e38f;
      float a1 = (col + 1 <= r) ? (float)cv.h[1] : -3.0e38f;
      v0[tn] = a0; v1[tn] = a1;
      mx = fmaxf(mx, fmaxf(a0, a1));
    }
  }
  #pragma unroll
  for (int d = 1; d < 64; d <<= 1) mx = fmaxf(mx, __shfl_xor(mx, d, 64));
  float sum = 0.f;
  #pragma unroll
  for (int tn = 0; tn < 32; ++tn) {
    if (tn < nt) {
      float p0 = (v0[tn] < -1.0e37f) ? 0.f : exp2f((v0[tn] - mx) * K2);
      float p1 = (v1[tn] < -1.0e37f) ? 0.f : exp2f((v1[tn] - mx) * K2);
      v0[tn] = p0; v1[tn] = p1;
      sum += p0 + p1;
    }
  }
  #pragma unroll
  for (int d = 1; d < 64; d <<= 1) sum += __shfl_xor(sum, d, 64);
  float inv = 1.0f / sum;
  #pragma unroll
  for (int tn = 0; tn < 32; ++tn) {
    if (tn < nt) {
      unsigned o = (unsigned)f2bf(v0[tn] * inv) | ((unsigned)f2bf(v1[tn] * inv) << 16);
      *(unsigned*)(base + tn * 128 + lane * 2) = o;
    }
  }
}

// ---------------- PV GEMM: z = P * V (panel A, Vt B) ----------------
// BM=256 (one panel), BN=128; 8 waves 4x2; paired panels (p, 15-p) per block.
// XCD-chunked: XCD x owns jobs jid = x*G + (j>>3); its 8 concurrent n8-slices
// share one panel-pair -> each panel HBM-fetched once per device.
__global__ __launch_bounds__(512, 2) void k_pv(
    const unsigned short* __restrict__ P,
    const unsigned short* __restrict__ Vt,
    float* __restrict__ z, int b0, int G)
{
  __shared__ unsigned short lds[4 * 12288];  // 96 KiB
  const int tid = threadIdx.x, lane = tid & 63, wid = tid >> 6;
  const int wm = wid >> 1, wn = wid & 1;     // 4 x 2 waves
  const int c = lane & 15, g = lane >> 4;
  const int x = blockIdx.x & 7;              // XCD
  const int j = blockIdx.x >> 3;             // [0, 8G)
  const int jid = x * G + (j >> 3);          // panel-pair job, [0, 8G)
  const int n8 = j & 7;                      // V column slice
  const int li = jid >> 3;
  const int pl = jid & 7;
  const int b = b0 + li;
  const unsigned short* Bg = Vt + ((size_t)b * DM + n8 * 128) * SEQ;

  for (int h = 0; h < 2; ++h) {
    const int p = h ? (15 - pl) : pl;
    const int NT = (p + 1) * 8;
    const size_t Kp = (size_t)(p + 1) * 256;
    const unsigned short* panel = P + (size_t)li * PBSTR + (size_t)tri(p) * 65536;

    f32x4 z4 = {0.f, 0.f, 0.f, 0.f};
    f32x4 acc[4][4];
    #pragma unroll
    for (int m = 0; m < 4; ++m)
      #pragma unroll
      for (int n = 0; n < 4; ++n) acc[m][n] = z4;

    run_gemm<256, 128, 4, 4>(lds, panel, Kp, Bg, SEQ, NT, tid, lane, wm, wn, acc);

    #pragma unroll
    for (int am = 0; am < 4; ++am) {
      int row = p * 256 + wm * 64 + am * 16 + g * 4;
      #pragma unroll
      for (int fn = 0; fn < 4; ++fn) {
        int col = n8 * 128 + wn * 64 + fn * 16 + c;
        #pragma unroll
        for (int r = 0; r < 4; ++r)
          z[((size_t)(b * SEQ + row + r)) * DM + col] = acc[am][fn][r];
      }
    }
    __syncthreads();  // full drain between paired jobs
  }
}

extern "C" void kernel_launch(void* const* d_in, const int* in_sizes, int n_in,
                              void* d_out, int out_size, void* d_ws, size_t ws_size,
                              hipStream_t stream) {
  const float* x    = (const float*)d_in[0];
  const float* cosT = (const float*)d_in[1];
  const float* sinT = (const float*)d_in[2];
  const float* Wq   = (const float*)d_in[3];
  const float* bq   = (const float*)d_in[4];
  const float* Wk   = (const float*)d_in[5];
  const float* bk   = (const float*)d_in[6];
  const float* Wv   = (const float*)d_in[7];
  const float* bv   = (const float*)d_in[8];
  float* z = (float*)d_out;

  char* ws = (char*)d_ws;
  unsigned short* xbf = (unsigned short*)(ws);
  unsigned short* Wqp = (unsigned short*)(ws + 33554432);
  unsigned short* Wkp = (unsigned short*)(ws + 35651584);
  unsigned short* Wvp = (unsigned short*)(ws + 37748736);
  float* bqp = (float*)(ws + 39845888);
  float* bkp = (float*)(ws + 39849984);
  float* bvp = (float*)(ws + 39854080);
  unsigned short* Qbf = (unsigned short*)(ws + 39858176);
  unsigned short* Kbf = (unsigned short*)(ws + 73412608);
  unsigned short* Vtb = (unsigned short*)(ws + 106967040);
  const size_t BASE = 140521472ULL;
  const size_t PER  = PBSTR * 2ULL;       // 17,825,792 B per batch of panels
  unsigned short* Sc = (unsigned short*)(ws + BASE);

  int G = 1;
  if (ws_size >= BASE + 4 * PER)      G = 4;
  else if (ws_size >= BASE + 2 * PER) G = 2;

  convert_kernel<<<dim3(2048), dim3(256), 0, stream>>>(
      x, Wq, Wk, Wv, bq, bk, bv, xbf, Wqp, Wkp, Wvp, bqp, bkp, bvp);

  k_gemm256<0><<<dim3(256), dim3(512), 0, stream>>>(xbf, Wqp, bqp, cosT, sinT, Qbf, 0, 1);
  k_gemm256<0><<<dim3(256), dim3(512), 0, stream>>>(xbf, Wkp, bkp, cosT, sinT, Kbf, 0, 1);
  k_gemm256<1><<<dim3(256), dim3(512), 0, stream>>>(xbf, Wvp, bvp, cosT, sinT, Vtb, 0, 1);

  for (int b0 = 0; b0 < NB; b0 += G) {
    k_gemm256<2><<<dim3(136 * G), dim3(512), 0, stream>>>(Qbf, Kbf, nullptr, nullptr, nullptr, Sc, b0, G);
    softmax_panel<<<dim3(1024 * G), dim3(256), 0, stream>>>(Sc);
    k_pv<<<dim3(64 * G), dim3(512), 0, stream>>>(Sc, Vtb, z, b0, G);
  }
}